// Round 1
// baseline (2234.000 us; speedup 1.0000x reference)
//
#include <hip/hip_runtime.h>
#include <math.h>

#define N_ROWS 16384
#define DIM 128
#define K_CODES 8192
#define INV_T 10.0f

// ws layout (float offsets)
#define OFF_EN    0u         // 8192*128
#define OFF_ZN    1048576u   // 16384*128
#define OFF_M     3145728u   // 16384
#define OFF_LINV  3162112u   // 16384
#define OFF_GAP   3178496u   // 16384
#define OFF_IDX   3194880u   // 16384 (int)
#define OFF_CNT   3211264u   // 8192 (uint)
#define OFF_P     3219456u   // 8192
#define OFF_MSE   3227648u   // 1

// ---------------- normalize rows: out = in / max(||in||, 1e-12) -------------
__global__ __launch_bounds__(256) void k_normalize(const float* __restrict__ in,
                                                   float* __restrict__ out, int rows) {
    int t = threadIdx.x;
    int wave = t >> 6, lane = t & 63;
    int row = blockIdx.x * 4 + wave;
    if (row >= rows) return;
    const float2 v = *reinterpret_cast<const float2*>(&in[(size_t)row * DIM + lane * 2]);
    float ss = v.x * v.x + v.y * v.y;
#pragma unroll
    for (int off = 32; off; off >>= 1) ss += __shfl_xor(ss, off);
    float nrm = fmaxf(sqrtf(ss), 1e-12f);
    float2 o; o.x = v.x / nrm; o.y = v.y / nrm;
    *reinterpret_cast<float2*>(&out[(size_t)row * DIM + lane * 2]) = o;
}

// stage ROWS x 128 tile of src (row-major) transposed into dst[128][ROWS]
template <int ROWS>
__device__ inline void stage_T(const float* __restrict__ src, size_t rowBase,
                               float* __restrict__ dst) {
    int t = threadIdx.x;
    constexpr int ITERS = ROWS * 32 / 256;  // 4 (ROWS=32) or 8 (ROWS=64)
    constexpr int RG = ROWS / 16;
    int r0 = t & 15, d40 = t >> 4;
#pragma unroll
    for (int it = 0; it < ITERS; ++it) {
        int r  = r0 + (it % RG) * 16;
        int d4 = d40 + (it / RG) * 16;
        float4 v = *reinterpret_cast<const float4*>(&src[(rowBase + r) * DIM + d4 * 4]);
        dst[(d4 * 4 + 0) * ROWS + r] = v.x;
        dst[(d4 * 4 + 1) * ROWS + r] = v.y;
        dst[(d4 * 4 + 2) * ROWS + r] = v.z;
        dst[(d4 * 4 + 3) * ROWS + r] = v.w;
    }
}

// -------- phase 1: per-row argmax / max / second-max / sum-exp --------------
__global__ __launch_bounds__(256, 2) void k_phase1(const float* __restrict__ zN,
                                                   const float* __restrict__ eN,
                                                   float* __restrict__ m_out,
                                                   float* __restrict__ linv_out,
                                                   float* __restrict__ gap_out,
                                                   int* __restrict__ idx_out) {
    __shared__ __align__(16) float zt[DIM * 32];   // [d][row], 16 KB
    __shared__ __align__(16) float ct[DIM * 64];   // [d][code], 32 KB
    int t = threadIdx.x;
    int tx = t & 31, ty = t >> 5;                  // tx: code dim, ty: row dim
    size_t rowBase = (size_t)blockIdx.x * 32;

    stage_T<32>(zN, rowBase, zt);

    float mrun[4], m2run[4], lrun[4];
    int irun[4];
#pragma unroll
    for (int i = 0; i < 4; ++i) { mrun[i] = -1e30f; m2run[i] = -1e30f; lrun[i] = 0.f; irun[i] = 0; }

    for (int ch = 0; ch < K_CODES / 64; ++ch) {
        __syncthreads();
        stage_T<64>(eN, (size_t)ch * 64, ct);
        __syncthreads();

        float acc[4][2];
#pragma unroll
        for (int i = 0; i < 4; ++i) { acc[i][0] = 0.f; acc[i][1] = 0.f; }

#pragma unroll 8
        for (int d = 0; d < DIM; ++d) {
            float4 za = *reinterpret_cast<const float4*>(&zt[d * 32 + ty * 4]);
            float2 cb = *reinterpret_cast<const float2*>(&ct[d * 64 + tx * 2]);
            acc[0][0] += za.x * cb.x; acc[0][1] += za.x * cb.y;
            acc[1][0] += za.y * cb.x; acc[1][1] += za.y * cb.y;
            acc[2][0] += za.z * cb.x; acc[2][1] += za.z * cb.y;
            acc[3][0] += za.w * cb.x; acc[3][1] += za.w * cb.y;
        }

        int cbase = ch * 64 + tx * 2;
#pragma unroll
        for (int i = 0; i < 4; ++i) {
            float v, v2; int c;
            if (acc[i][0] >= acc[i][1]) { v = acc[i][0]; c = cbase;     v2 = acc[i][1]; }
            else                        { v = acc[i][1]; c = cbase + 1; v2 = acc[i][0]; }
#pragma unroll
            for (int off = 1; off < 32; off <<= 1) {
                float ov  = __shfl_xor(v, off);
                int   oc  = __shfl_xor(c, off);
                float ov2 = __shfl_xor(v2, off);
                if (ov > v || (ov == v && oc < c)) { v2 = fmaxf(v, ov2); v = ov; c = oc; }
                else                               { v2 = fmaxf(v2, ov); }
            }
            float mo = mrun[i];
            float mn = fmaxf(mo, v);
            float ps = __expf((acc[i][0] - mn) * INV_T) + __expf((acc[i][1] - mn) * INV_T);
#pragma unroll
            for (int off = 1; off < 32; off <<= 1) ps += __shfl_xor(ps, off);
            lrun[i] = lrun[i] * __expf((mo - mn) * INV_T) + ps;
            if (v > mo) { m2run[i] = fmaxf(mo, v2); mrun[i] = v; irun[i] = c; }
            else        { m2run[i] = fmaxf(m2run[i], v); }
        }
    }

    if (tx == 0) {
#pragma unroll
        for (int i = 0; i < 4; ++i) {
            size_t r = rowBase + ty * 4 + i;
            m_out[r]    = mrun[i];
            linv_out[r] = 1.0f / lrun[i];
            gap_out[r]  = mrun[i] - m2run[i];
            idx_out[r]  = irun[i];
        }
    }
}

// -------- fp64 argmax refinement for rows with tiny top-2 gap ---------------
__global__ __launch_bounds__(256) void k_refine(const float* __restrict__ zN,
                                                const float* __restrict__ eN,
                                                const float* __restrict__ gap,
                                                int* __restrict__ idx_out) {
    int row = blockIdx.x;
    if (gap[row] >= 2e-4f) return;
    __shared__ float zrow[DIM];
    __shared__ double sred[4];
    __shared__ int ired[4];
    int t = threadIdx.x;
    if (t < DIM) zrow[t] = zN[(size_t)row * DIM + t];
    __syncthreads();
    double best = -1e300; int bidx = 0;
    for (int k = t; k < K_CODES; k += 256) {
        const float* e = &eN[(size_t)k * DIM];
        double s = 0.0;
#pragma unroll 4
        for (int d = 0; d < DIM; ++d) s += (double)zrow[d] * (double)e[d];
        if (s > best || (s == best && k < bidx)) { best = s; bidx = k; }
    }
#pragma unroll
    for (int off = 1; off < 64; off <<= 1) {
        double ob = __shfl_xor(best, off);
        int    oi = __shfl_xor(bidx, off);
        if (ob > best || (ob == best && oi < bidx)) { best = ob; bidx = oi; }
    }
    int lane = t & 63, wv = t >> 6;
    if (lane == 0) { sred[wv] = best; ired[wv] = bidx; }
    __syncthreads();
    if (t == 0) {
        for (int w = 1; w < 4; ++w)
            if (sred[w] > best || (sred[w] == best && ired[w] < bidx)) { best = sred[w]; bidx = ired[w]; }
        idx_out[row] = bidx;
    }
}

__global__ void k_counts(const int* __restrict__ idx, unsigned int* __restrict__ counts) {
    int i = blockIdx.x * 256 + threadIdx.x;
    atomicAdd(&counts[idx[i]], 1u);
}

// -------- phase 2: P_sum[k] = sum_n exp((s_nk - m_n)/T) / l_n ---------------
__global__ __launch_bounds__(256, 2) void k_phase2(const float* __restrict__ zN,
                                                   const float* __restrict__ eN,
                                                   const float* __restrict__ m_in,
                                                   const float* __restrict__ linv_in,
                                                   float* __restrict__ P_sum) {
    __shared__ __align__(16) float zt[DIM * 32];
    __shared__ __align__(16) float ct[DIM * 64];
    int t = threadIdx.x;
    int tx = t & 31, ty = t >> 5;
    int ctile = blockIdx.x & 127;
    int slice = blockIdx.x >> 7;   // 4 row-slices of 4096
    size_t cBase = (size_t)ctile * 64;

    stage_T<64>(eN, cBase, ct);

    float pacc0 = 0.f, pacc1 = 0.f;
    for (int ch = 0; ch < 128; ++ch) {
        size_t rowBase = (size_t)slice * 4096 + (size_t)ch * 32;
        __syncthreads();
        stage_T<32>(zN, rowBase, zt);
        __syncthreads();

        float acc[4][2];
#pragma unroll
        for (int i = 0; i < 4; ++i) { acc[i][0] = 0.f; acc[i][1] = 0.f; }

#pragma unroll 8
        for (int d = 0; d < DIM; ++d) {
            float4 za = *reinterpret_cast<const float4*>(&zt[d * 32 + ty * 4]);
            float2 cb = *reinterpret_cast<const float2*>(&ct[d * 64 + tx * 2]);
            acc[0][0] += za.x * cb.x; acc[0][1] += za.x * cb.y;
            acc[1][0] += za.y * cb.x; acc[1][1] += za.y * cb.y;
            acc[2][0] += za.z * cb.x; acc[2][1] += za.z * cb.y;
            acc[3][0] += za.w * cb.x; acc[3][1] += za.w * cb.y;
        }
#pragma unroll
        for (int i = 0; i < 4; ++i) {
            size_t r = rowBase + ty * 4 + i;
            float mi = m_in[r];
            float li = linv_in[r];
            pacc0 += __expf((acc[i][0] - mi) * INV_T) * li;
            pacc1 += __expf((acc[i][1] - mi) * INV_T) * li;
        }
    }
    __syncthreads();
    float* red = zt;  // reuse
    red[ty * 64 + tx * 2 + 0] = pacc0;
    red[ty * 64 + tx * 2 + 1] = pacc1;
    __syncthreads();
    if (t < 64) {
        float s = 0.f;
#pragma unroll
        for (int y = 0; y < 8; ++y) s += red[y * 64 + t];
        atomicAdd(&P_sum[cBase + t], s);
    }
}

// -------- gather z_q_st + commit-loss partial -------------------------------
__global__ __launch_bounds__(256) void k_gather(const float* __restrict__ z,
                                                const float* __restrict__ W,
                                                const int* __restrict__ idx,
                                                float* __restrict__ out,
                                                float* __restrict__ mse) {
    int v = blockIdx.x * 256 + threadIdx.x;  // float4 index
    int row = v >> 5;
    int id = idx[row];
    float4 q  = *reinterpret_cast<const float4*>(&W[(size_t)id * DIM + (v & 31) * 4]);
    float4 zz = *reinterpret_cast<const float4*>(&z[(size_t)v * 4]);
    float dx = q.x - zz.x, dy = q.y - zz.y, dz = q.z - zz.z, dw = q.w - zz.w;
    float4 o; o.x = zz.x + dx; o.y = zz.y + dy; o.z = zz.z + dz; o.w = zz.w + dw;
    *reinterpret_cast<float4*>(&out[(size_t)v * 4]) = o;
    float e = dx * dx + dy * dy + dz * dz + dw * dw;
#pragma unroll
    for (int off = 1; off < 64; off <<= 1) e += __shfl_xor(e, off);
    __shared__ float red[4];
    int lane = threadIdx.x & 63, wv = threadIdx.x >> 6;
    if (lane == 0) red[wv] = e;
    __syncthreads();
    if (threadIdx.x == 0) atomicAdd(mse, red[0] + red[1] + red[2] + red[3]);
}

// -------- finalize scalars ---------------------------------------------------
__global__ __launch_bounds__(256) void k_finalize(const unsigned int* __restrict__ counts,
                                                  const float* __restrict__ P_sum,
                                                  const float* __restrict__ mse,
                                                  float* __restrict__ out) {
    int t = threadIdx.x;
    float s1 = 0.f, s2 = 0.f;
    for (int k = t; k < K_CODES; k += 256) {
        float em = (float)counts[k] * (1.0f / 16384.0f);
        s1 += em * logf(em + 1e-8f);
        float p = P_sum[k] * (1.0f / 16384.0f) + 1e-8f;
        s2 += p * logf(p);
    }
#pragma unroll
    for (int off = 1; off < 64; off <<= 1) {
        s1 += __shfl_xor(s1, off);
        s2 += __shfl_xor(s2, off);
    }
    __shared__ float r1[4], r2[4];
    int lane = t & 63, wv = t >> 6;
    if (lane == 0) { r1[wv] = s1; r2[wv] = s2; }
    __syncthreads();
    if (t == 0) {
        float S1 = r1[0] + r1[1] + r1[2] + r1[3];
        float S2 = r2[0] + r2[1] + r2[2] + r2[3];
        out[2097152] = 1.25f * mse[0] * (1.0f / 2097152.0f);  // commit loss
        out[2097153] = expf(-S1);                             // perplexity
        out[2097154] = -S2;                                   // entropy loss
    }
}

extern "C" void kernel_launch(void* const* d_in, const int* in_sizes, int n_in,
                              void* d_out, int out_size, void* d_ws, size_t ws_size,
                              hipStream_t stream) {
    (void)in_sizes; (void)n_in; (void)out_size; (void)ws_size;
    const float* z = (const float*)d_in[0];
    const float* W = (const float*)d_in[1];
    float* ws = (float*)d_ws;
    float* eN     = ws + OFF_EN;
    float* zN     = ws + OFF_ZN;
    float* m      = ws + OFF_M;
    float* linv   = ws + OFF_LINV;
    float* gapA   = ws + OFF_GAP;
    int*   idx    = (int*)(ws + OFF_IDX);
    unsigned int* counts = (unsigned int*)(ws + OFF_CNT);
    float* P   = ws + OFF_P;
    float* mse = ws + OFF_MSE;
    float* out = (float*)d_out;

    hipMemsetAsync(ws + OFF_CNT, 0, (size_t)(K_CODES * 2 + 1) * sizeof(float), stream);
    k_normalize<<<N_ROWS / 4, 256, 0, stream>>>(z, zN, N_ROWS);
    k_normalize<<<K_CODES / 4, 256, 0, stream>>>(W, eN, K_CODES);
    k_phase1<<<N_ROWS / 32, 256, 0, stream>>>(zN, eN, m, linv, gapA, idx);
    k_refine<<<N_ROWS, 256, 0, stream>>>(zN, eN, gapA, idx);
    k_counts<<<N_ROWS / 256, 256, 0, stream>>>(idx, counts);
    k_phase2<<<512, 256, 0, stream>>>(zN, eN, m, linv, P);
    k_gather<<<(N_ROWS * DIM / 4) / 256, 256, 0, stream>>>(z, W, idx, out, mse);
    k_finalize<<<1, 256, 0, stream>>>(counts, P, mse, out);
}

// Round 2
// 2179.754 us; speedup vs baseline: 1.0249x; 1.0249x over previous
//
#include <hip/hip_runtime.h>
#include <hip/hip_bf16.h>
#include <math.h>

#define N_ROWS 16384
#define DIM 128
#define K_CODES 8192
#define KPRIME 384            // split-bf16 contraction length: [h|l|h] . [h|h|l]
#define EPSF 5e-4f            // runner-up flag threshold (split err ~5e-6 -> 100x margin)

// ---- workspace layout (float offsets) --------------------------------------
#define OFF_EN       0u          // eN fp32: 8192*128            = 1,048,576 f
#define OFF_ZN       1048576u    // zN fp32: 16384*128           = 2,097,152 f
#define OFF_EP       3145728u    // Ep bf16: 8192*384  (1,572,864 f)
#define OFF_ZP       4718592u    // Zp bf16: 16384*384 (3,145,728 f)
#define OFF_PART     7864320u    // phase1 partials: 4*16384 float4 = 262,144 f
#define OFF_M        8126464u    // 16384
#define OFF_LINV     8142848u    // 16384
#define OFF_IDX      8159232u    // 16384 int
#define OFF_FLAGLIST 8175616u    // 16384 int
#define OFF_CNT      8192000u    // 8192 u32   <-- memset region starts here
#define OFF_P        8200192u    // 8192 f
#define OFF_MSE      8208384u    // 1
#define OFF_NFLAG    8208385u    // 1 int
#define OFF_REFBUF   8208386u    // 16384 u64 (8B aligned)
#define MEMSET_BYTES 196616u     // CNT..REFBUF end

typedef __bf16 bf16x8 __attribute__((ext_vector_type(8)));
typedef float  f32x4  __attribute__((ext_vector_type(4)));
#define MFMA16(a, b, c) __builtin_amdgcn_mfma_f32_16x16x32_bf16(a, b, c, 0, 0, 0)

__device__ __forceinline__ void gld_lds16(const ushort* g, ushort* l) {
    __builtin_amdgcn_global_load_lds(
        (const __attribute__((address_space(1))) unsigned int*)g,
        (__attribute__((address_space(3))) unsigned int*)l, 16, 0, 0);
}

__device__ __forceinline__ ushort f2bf(float x) {
    __hip_bfloat16 b = __float2bfloat16(x);
    return *reinterpret_cast<ushort*>(&b);
}
__device__ __forceinline__ float bf2f(ushort u) {
    __hip_bfloat16 b = *reinterpret_cast<__hip_bfloat16*>(&u);
    return __bfloat162float(b);
}

// tiled+swizzled bf16 store: element (tile row r, k) of tile T ->
// chunk q = r*8 + ((k>>3 & 7) ^ (r&7)) within kgroup g=k>>6; 16B chunks.
__device__ __forceinline__ void bf_store2(ushort* __restrict__ P, int T, int r,
                                          int rx, int k, ushort e0, ushort e1) {
    int g = k >> 6, kp = (k >> 3) & 7, j = k & 7;
    int off = ((((T * 6 + g) << 10) + (r << 3) + (kp ^ rx)) << 3) + j;
    *reinterpret_cast<ushort2*>(&P[off]) = make_ushort2(e0, e1);
}

// ---- prep: normalize rows (fp32) + write split-bf16 tiled layout -----------
// mode 0 (z): k-layout [hi | lo | hi];  mode 1 (e): [hi | hi | lo]
__global__ __launch_bounds__(256) void k_prep(const float* __restrict__ src,
                                              float* __restrict__ dstN,
                                              ushort* __restrict__ dstP, int mode) {
    int t = threadIdx.x, w = t >> 6, lane = t & 63;
    int row = blockIdx.x * 4 + w;
    float2 v = *reinterpret_cast<const float2*>(&src[(size_t)row * DIM + lane * 2]);
    float ss = v.x * v.x + v.y * v.y;
#pragma unroll
    for (int off = 32; off; off >>= 1) ss += __shfl_xor(ss, off);
    float nrm = fmaxf(sqrtf(ss), 1e-12f);
    float a = v.x / nrm, b = v.y / nrm;
    *reinterpret_cast<float2*>(&dstN[(size_t)row * DIM + lane * 2]) = make_float2(a, b);
    ushort ha = f2bf(a), hb = f2bf(b);
    ushort la = f2bf(a - bf2f(ha)), lb = f2bf(b - bf2f(hb));
    int T = row >> 7, r = row & 127, rx = r & 7, d = lane * 2;
    bf_store2(dstP, T, r, rx, d, ha, hb);
    if (mode == 0) {
        bf_store2(dstP, T, r, rx, 128 + d, la, lb);
        bf_store2(dstP, T, r, rx, 256 + d, ha, hb);
    } else {
        bf_store2(dstP, T, r, rx, 128 + d, ha, hb);
        bf_store2(dstP, T, r, rx, 256 + d, la, lb);
    }
}

// ---- phase 1: MFMA GEMM + online (max, argmax|flag, sumexp) ----------------
// grid 512: rg = b>>2 (128 row-groups of 128), slice = b&3 (2048 codes each)
__global__ __launch_bounds__(256, 2) void k_p1(const ushort* __restrict__ Zp,
                                               const ushort* __restrict__ Ep,
                                               float4* __restrict__ part) {
    __shared__ ushort Au[8192];  // 16KB: A tile (128 rows x 64 k), swizzled
    __shared__ ushort Bu[8192];  // 16KB: B tile (128 codes x 64 k)
    int t = threadIdx.x, lane = t & 63, w = t >> 6;
    int rg = blockIdx.x >> 2, slice = blockIdx.x & 3;
    int wm = w >> 1, wn = w & 1;           // wave grid 2x2 over 128x128
    int n15 = lane & 15, quad = lane >> 4;

    float sm[16], sl[16];
    unsigned si[16];
#pragma unroll
    for (int s = 0; s < 16; ++s) { sm[s] = -1e30f; sl[s] = 0.f; si[s] = 0u; }

    for (int ch = 0; ch < 16; ++ch) {
        int ctile = slice * 16 + ch;
        f32x4 acc[4][4];
#pragma unroll
        for (int i = 0; i < 4; ++i)
#pragma unroll
            for (int j = 0; j < 4; ++j) acc[i][j] = (f32x4)0.0f;

        for (int g = 0; g < 6; ++g) {
            __syncthreads();
            const ushort* ga = Zp + (((size_t)rg * 6 + g) << 13);
            const ushort* gb = Ep + (((size_t)ctile * 6 + g) << 13);
#pragma unroll
            for (int rr = 0; rr < 4; ++rr) {
                int q = (rr * 256 + t) << 3;
                gld_lds16(ga + q, &Au[q]);
                gld_lds16(gb + q, &Bu[q]);
            }
            __syncthreads();
#pragma unroll
            for (int kl = 0; kl < 2; ++kl) {
                int kp = kl * 4 + quad;
                bf16x8 af[4], bf[4];
#pragma unroll
                for (int ms = 0; ms < 4; ++ms) {
                    int r = wm * 64 + ms * 16 + n15;
                    af[ms] = *reinterpret_cast<const bf16x8*>(&Au[((r << 3) + (kp ^ (r & 7))) << 3]);
                }
#pragma unroll
                for (int ns = 0; ns < 4; ++ns) {
                    int c = wn * 64 + ns * 16 + n15;
                    bf[ns] = *reinterpret_cast<const bf16x8*>(&Bu[((c << 3) + (kp ^ (c & 7))) << 3]);
                }
#pragma unroll
                for (int ms = 0; ms < 4; ++ms)
#pragma unroll
                    for (int ns = 0; ns < 4; ++ns)
                        acc[ms][ns] = MFMA16(af[ms], bf[ns], acc[ms][ns]);
            }
        }
        // epilogue: per-lane online streams (codes ascend within each stream)
        unsigned cbase = slice * 2048 + ch * 128 + wn * 64 + n15;
#pragma unroll
        for (int ms = 0; ms < 4; ++ms)
#pragma unroll
            for (int reg = 0; reg < 4; ++reg) {
                int s = ms * 4 + reg;
                float m = sm[s], l = sl[s];
                unsigned idxf = si[s];
#pragma unroll
                for (int ns = 0; ns < 4; ++ns) {
                    float v = acc[ms][ns][reg];
                    unsigned code = cbase + ns * 16;
                    float d = v - m;
                    bool up = d > 0.f;
                    float e = __expf((up ? -d : d) * 10.f);
                    l = up ? fmaf(l, e, 1.0f) : (l + e);
                    bool near = fabsf(d) < EPSF;
                    unsigned nf = idxf | (near ? 0x80000000u : 0u);
                    idxf = up ? (code | (nf & 0x80000000u)) : nf;
                    m = up ? v : m;
                }
                sm[s] = m; sl[s] = l; si[s] = idxf;
            }
    }
    // cross-lane merge over the 16-lane col group
#pragma unroll
    for (int ms = 0; ms < 4; ++ms)
#pragma unroll
        for (int reg = 0; reg < 4; ++reg) {
            int s = ms * 4 + reg;
            float m = sm[s], l = sl[s];
            unsigned idxf = si[s];
#pragma unroll
            for (int off = 1; off < 16; off <<= 1) {
                float om = __shfl_xor(m, off);
                float ol = __shfl_xor(l, off);
                unsigned oi = (unsigned)__shfl_xor((int)idxf, off);
                bool near = fabsf(m - om) < EPSF;
                float nm = fmaxf(m, om);
                l = l * __expf((m - nm) * 10.f) + ol * __expf((om - nm) * 10.f);
                unsigned fl = ((idxf | oi) & 0x80000000u) | (near ? 0x80000000u : 0u);
                unsigned mi = idxf & 0x7FFFFFFFu, moi = oi & 0x7FFFFFFFu;
                bool take = (om > m) || (om == m && moi < mi);
                idxf = (take ? moi : mi) | fl;
                m = nm;
            }
            if (n15 == 0) {
                int row = rg * 128 + wm * 64 + ms * 16 + quad * 4 + reg;
                part[slice * N_ROWS + row] = make_float4(m, l, __uint_as_float(idxf), 0.f);
            }
        }
}

// ---- merge 4 slice-partials per row ----------------------------------------
__global__ __launch_bounds__(256) void k_merge(const float4* __restrict__ part,
                                               float* __restrict__ m_out,
                                               float* __restrict__ linv_out,
                                               int* __restrict__ idx_out,
                                               int* __restrict__ flaglist,
                                               int* __restrict__ nflag) {
    int row = blockIdx.x * 256 + threadIdx.x;
    float m = -1e30f, l = 0.f;
    unsigned idxf = 0u;
#pragma unroll
    for (int s = 0; s < 4; ++s) {
        float4 p = part[s * N_ROWS + row];
        float om = p.x, ol = p.y;
        unsigned oi = __float_as_uint(p.z);
        bool near = fabsf(m - om) < EPSF;
        float nm = fmaxf(m, om);
        l = l * __expf((m - nm) * 10.f) + ol * __expf((om - nm) * 10.f);
        unsigned fl = ((idxf | oi) & 0x80000000u) | ((near && s > 0) ? 0x80000000u : 0u);
        unsigned mi = idxf & 0x7FFFFFFFu, moi = oi & 0x7FFFFFFFu;
        bool take = (om > m) || (om == m && moi < mi);
        idxf = (take ? moi : mi) | fl;
        m = nm;
    }
    m_out[row] = m;
    linv_out[row] = 1.0f / l;
    idx_out[row] = (int)(idxf & 0x7FFFFFFFu);
    if (idxf & 0x80000000u) {
        int pos = atomicAdd(nflag, 1);
        flaglist[pos] = row;
    }
}

// ---- fp64 exact re-argmax for flagged rows (compacted, code-sliced) --------
// grid 8192: rowg = b>>4 (8 flagged rows each, capacity 4096), csl = b&15 (512 codes)
__global__ __launch_bounds__(256) void k_refine64(const float* __restrict__ zN,
                                                  const float* __restrict__ eN,
                                                  const int* __restrict__ flaglist,
                                                  const int* __restrict__ nflag,
                                                  unsigned long long* __restrict__ refbuf) {
    int rowg = blockIdx.x >> 4, csl = blockIdx.x & 15;
    int nf = *nflag;
    if (nf > 4096) nf = 4096;
    int base = rowg * 8;
    if (base >= nf) return;
    __shared__ float zl[1024];
    int t = threadIdx.x;
    for (int i = t; i < 1024; i += 256) {
        int rr = base + (i >> 7);
        zl[i] = (rr < nf) ? zN[(size_t)flaglist[rr] * DIM + (i & 127)] : 0.f;
    }
    __syncthreads();
    int ri = t >> 5, lane32 = t & 31;
    if (base + ri >= nf) return;
    int row = flaglist[base + ri];
    double best = -1e300;
    int bc = 0;
    for (int j = 0; j < 16; ++j) {
        int c = csl * 512 + lane32 + j * 32;
        const float* e = &eN[(size_t)c * DIM];
        double s = 0.0;
#pragma unroll 4
        for (int d = 0; d < DIM; ++d) s += (double)zl[ri * DIM + d] * (double)e[d];
        if (s > best || (s == best && c < bc)) { best = s; bc = c; }
    }
#pragma unroll
    for (int off = 1; off < 32; off <<= 1) {
        double ob = __shfl_xor(best, off);
        int oc = __shfl_xor(bc, off);
        if (ob > best || (ob == best && oc < bc)) { best = ob; bc = oc; }
    }
    if (lane32 == 0) {
        float bf = (float)best;
        unsigned u = __float_as_uint(bf);
        u ^= (unsigned)(((int)u >> 31)) | 0x80000000u;  // monotone float key
        unsigned long long key = ((unsigned long long)u << 32) | (unsigned)(8191 - bc);
        atomicMax(&refbuf[row], key);
    }
}

__global__ __launch_bounds__(256) void k_fixidx(const int* __restrict__ flaglist,
                                                const int* __restrict__ nflag,
                                                const unsigned long long* __restrict__ refbuf,
                                                int* __restrict__ idx) {
    int i = blockIdx.x * 256 + threadIdx.x;
    int nf = *nflag;
    if (nf > 4096) nf = 4096;
    if (i < nf) {
        int row = flaglist[i];
        idx[row] = 8191 - (int)(refbuf[row] & 0xFFFFFFFFull);
    }
}

__global__ void k_counts(const int* __restrict__ idx, unsigned int* __restrict__ counts) {
    int i = blockIdx.x * 256 + threadIdx.x;
    atomicAdd(&counts[idx[i]], 1u);
}

// ---- phase 2: rotated GEMM (codes = M); P_sum[k] += exp((s-m)*10)*linv -----
// grid 512: cg = b>>3 (64 code-groups of 128), rs = b&7 (2048 rows each)
__global__ __launch_bounds__(256, 2) void k_p2(const ushort* __restrict__ Zp,
                                               const ushort* __restrict__ Ep,
                                               const float* __restrict__ m_in,
                                               const float* __restrict__ linv_in,
                                               float* __restrict__ P_sum) {
    __shared__ ushort Au[8192];  // codes tile
    __shared__ ushort Bu[8192];  // rows tile
    int t = threadIdx.x, lane = t & 63, w = t >> 6;
    int cg = blockIdx.x >> 3, rs = blockIdx.x & 7;
    int wm = w >> 1, wn = w & 1;
    int n15 = lane & 15, quad = lane >> 4;

    float pacc[16];
#pragma unroll
    for (int s = 0; s < 16; ++s) pacc[s] = 0.f;

    for (int ch = 0; ch < 16; ++ch) {
        int rtile = rs * 16 + ch;
        f32x4 acc[4][4];
#pragma unroll
        for (int i = 0; i < 4; ++i)
#pragma unroll
            for (int j = 0; j < 4; ++j) acc[i][j] = (f32x4)0.0f;

        for (int g = 0; g < 6; ++g) {
            __syncthreads();
            const ushort* ga = Ep + (((size_t)cg * 6 + g) << 13);
            const ushort* gb = Zp + (((size_t)rtile * 6 + g) << 13);
#pragma unroll
            for (int rr = 0; rr < 4; ++rr) {
                int q = (rr * 256 + t) << 3;
                gld_lds16(ga + q, &Au[q]);
                gld_lds16(gb + q, &Bu[q]);
            }
            __syncthreads();
#pragma unroll
            for (int kl = 0; kl < 2; ++kl) {
                int kp = kl * 4 + quad;
                bf16x8 af[4], bf[4];
#pragma unroll
                for (int ms = 0; ms < 4; ++ms) {
                    int r = wm * 64 + ms * 16 + n15;
                    af[ms] = *reinterpret_cast<const bf16x8*>(&Au[((r << 3) + (kp ^ (r & 7))) << 3]);
                }
#pragma unroll
                for (int ns = 0; ns < 4; ++ns) {
                    int c = wn * 64 + ns * 16 + n15;
                    bf[ns] = *reinterpret_cast<const bf16x8*>(&Bu[((c << 3) + (kp ^ (c & 7))) << 3]);
                }
#pragma unroll
                for (int ms = 0; ms < 4; ++ms)
#pragma unroll
                    for (int ns = 0; ns < 4; ++ns)
                        acc[ms][ns] = MFMA16(af[ms], bf[ns], acc[ms][ns]);
            }
        }
        int rbase = rs * 2048 + ch * 128 + wn * 64 + n15;
        float mr[4], li[4];
#pragma unroll
        for (int ns = 0; ns < 4; ++ns) {
            mr[ns] = m_in[rbase + ns * 16];
            li[ns] = linv_in[rbase + ns * 16];
        }
#pragma unroll
        for (int ms = 0; ms < 4; ++ms)
#pragma unroll
            for (int reg = 0; reg < 4; ++reg) {
                int s = ms * 4 + reg;
                float p = pacc[s];
#pragma unroll
                for (int ns = 0; ns < 4; ++ns)
                    p = fmaf(__expf((acc[ms][ns][reg] - mr[ns]) * 10.f), li[ns], p);
                pacc[s] = p;
            }
    }
#pragma unroll
    for (int s = 0; s < 16; ++s) {
#pragma unroll
        for (int off = 1; off < 16; off <<= 1) pacc[s] += __shfl_xor(pacc[s], off);
    }
    if (n15 == 0) {
#pragma unroll
        for (int ms = 0; ms < 4; ++ms)
#pragma unroll
            for (int reg = 0; reg < 4; ++reg)
                atomicAdd(&P_sum[cg * 128 + wm * 64 + ms * 16 + quad * 4 + reg],
                          pacc[ms * 4 + reg]);
    }
}

// ---- gather z_q_st + commit-loss partial (round-1 verified) ----------------
__global__ __launch_bounds__(256) void k_gather(const float* __restrict__ z,
                                                const float* __restrict__ W,
                                                const int* __restrict__ idx,
                                                float* __restrict__ out,
                                                float* __restrict__ mse) {
    int v = blockIdx.x * 256 + threadIdx.x;
    int row = v >> 5;
    int id = idx[row];
    float4 q = *reinterpret_cast<const float4*>(&W[(size_t)id * DIM + (v & 31) * 4]);
    float4 zz = *reinterpret_cast<const float4*>(&z[(size_t)v * 4]);
    float dx = q.x - zz.x, dy = q.y - zz.y, dz = q.z - zz.z, dw = q.w - zz.w;
    *reinterpret_cast<float4*>(&out[(size_t)v * 4]) = q;
    float e = dx * dx + dy * dy + dz * dz + dw * dw;
#pragma unroll
    for (int off = 1; off < 64; off <<= 1) e += __shfl_xor(e, off);
    __shared__ float red[4];
    int lane = threadIdx.x & 63, wv = threadIdx.x >> 6;
    if (lane == 0) red[wv] = e;
    __syncthreads();
    if (threadIdx.x == 0) atomicAdd(mse, red[0] + red[1] + red[2] + red[3]);
}

// ---- finalize scalars (round-1 verified) -----------------------------------
__global__ __launch_bounds__(256) void k_finalize(const unsigned int* __restrict__ counts,
                                                  const float* __restrict__ P_sum,
                                                  const float* __restrict__ mse,
                                                  float* __restrict__ out) {
    int t = threadIdx.x;
    float s1 = 0.f, s2 = 0.f;
    for (int k = t; k < K_CODES; k += 256) {
        float em = (float)counts[k] * (1.0f / 16384.0f);
        s1 += em * logf(em + 1e-8f);
        float p = P_sum[k] * (1.0f / 16384.0f) + 1e-8f;
        s2 += p * logf(p);
    }
#pragma unroll
    for (int off = 1; off < 64; off <<= 1) {
        s1 += __shfl_xor(s1, off);
        s2 += __shfl_xor(s2, off);
    }
    __shared__ float r1[4], r2[4];
    int lane = t & 63, wv = t >> 6;
    if (lane == 0) { r1[wv] = s1; r2[wv] = s2; }
    __syncthreads();
    if (t == 0) {
        float S1 = r1[0] + r1[1] + r1[2] + r1[3];
        float S2 = r2[0] + r2[1] + r2[2] + r2[3];
        out[2097152] = 1.25f * mse[0] * (1.0f / 2097152.0f);
        out[2097153] = expf(-S1);
        out[2097154] = -S2;
    }
}

extern "C" void kernel_launch(void* const* d_in, const int* in_sizes, int n_in,
                              void* d_out, int out_size, void* d_ws, size_t ws_size,
                              hipStream_t stream) {
    (void)in_sizes; (void)n_in; (void)out_size; (void)ws_size;
    const float* z = (const float*)d_in[0];
    const float* W = (const float*)d_in[1];
    float* ws = (float*)d_ws;
    float* eN = ws + OFF_EN;
    float* zN = ws + OFF_ZN;
    ushort* Ep = (ushort*)(ws + OFF_EP);
    ushort* Zp = (ushort*)(ws + OFF_ZP);
    float4* part = (float4*)(ws + OFF_PART);
    float* m = ws + OFF_M;
    float* linv = ws + OFF_LINV;
    int* idx = (int*)(ws + OFF_IDX);
    int* flaglist = (int*)(ws + OFF_FLAGLIST);
    unsigned int* counts = (unsigned int*)(ws + OFF_CNT);
    float* P = ws + OFF_P;
    float* mse = ws + OFF_MSE;
    int* nflag = (int*)(ws + OFF_NFLAG);
    unsigned long long* refbuf = (unsigned long long*)(ws + OFF_REFBUF);
    float* out = (float*)d_out;

    hipMemsetAsync(ws + OFF_CNT, 0, MEMSET_BYTES, stream);
    k_prep<<<N_ROWS / 4, 256, 0, stream>>>(z, zN, Zp, 0);
    k_prep<<<K_CODES / 4, 256, 0, stream>>>(W, eN, Ep, 1);
    k_p1<<<512, 256, 0, stream>>>(Zp, Ep, part);
    k_merge<<<N_ROWS / 256, 256, 0, stream>>>(part, m, linv, idx, flaglist, nflag);
    k_refine64<<<8192, 256, 0, stream>>>(zN, eN, flaglist, nflag, refbuf);
    k_fixidx<<<16, 256, 0, stream>>>(flaglist, nflag, refbuf, idx);
    k_counts<<<N_ROWS / 256, 256, 0, stream>>>(idx, counts);
    k_p2<<<512, 256, 0, stream>>>(Zp, Ep, m, linv, P);
    k_gather<<<(N_ROWS * DIM / 4) / 256, 256, 0, stream>>>(z, W, idx, out, mse);
    k_finalize<<<1, 256, 0, stream>>>(counts, P, mse, out);
}

// Round 3
// 964.411 us; speedup vs baseline: 2.3164x; 2.2602x over previous
//
#include <hip/hip_runtime.h>
#include <hip/hip_bf16.h>
#include <math.h>

#define N_ROWS 16384
#define DIM 128
#define K_CODES 8192
#define EPSF 7e-5f            // top-2 gap flag threshold (split-bf16 err ~1e-6)

// ---- workspace layout (float offsets) --------------------------------------
#define OFF_EN       0u          // eN fp32: 8192*128            = 1,048,576 f
#define OFF_ZN       1048576u    // zN fp32: 16384*128           = 2,097,152 f
#define OFF_EP       3145728u    // Ep bf16: 8192*384  (1,572,864 f)
#define OFF_ZP       4718592u    // Zp bf16: 16384*384 (3,145,728 f)
#define OFF_PART     7864320u    // phase1 partials: 4*16384 float4 = 262,144 f
#define OFF_M        8126464u    // 16384
#define OFF_LINV     8142848u    // 16384
#define OFF_IDX      8159232u    // 16384 int
#define OFF_FLAGLIST 8175616u    // 16384 int
#define OFF_CNT      8192000u    // 8192 u32   <-- memset region starts here
#define OFF_P        8200192u    // 8192 f
#define OFF_MSE      8208384u    // 1
#define OFF_NFLAG    8208385u    // 1 int
#define MEMSET_BYTES 65544u      // counts + P + mse + nflag

typedef __bf16 bf16x8 __attribute__((ext_vector_type(8)));
typedef float  f32x4  __attribute__((ext_vector_type(4)));
#define MFMA16(a, b, c) __builtin_amdgcn_mfma_f32_16x16x32_bf16(a, b, c, 0, 0, 0)

__device__ __forceinline__ void gld_lds16(const ushort* g, ushort* l) {
    __builtin_amdgcn_global_load_lds(
        (const __attribute__((address_space(1))) unsigned int*)g,
        (__attribute__((address_space(3))) unsigned int*)l, 16, 0, 0);
}

__device__ __forceinline__ ushort f2bf(float x) {
    __hip_bfloat16 b = __float2bfloat16(x);
    return *reinterpret_cast<ushort*>(&b);
}
__device__ __forceinline__ float bf2f(ushort u) {
    __hip_bfloat16 b = *reinterpret_cast<__hip_bfloat16*>(&u);
    return __bfloat162float(b);
}

// tiled+swizzled bf16 store: element (tile row r, k) of tile T ->
// chunk q = r*8 + ((k>>3 & 7) ^ (r&7)) within kgroup g=k>>6; 16B chunks.
__device__ __forceinline__ void bf_store2(ushort* __restrict__ P, int T, int r,
                                          int rx, int k, ushort e0, ushort e1) {
    int g = k >> 6, kp = (k >> 3) & 7, j = k & 7;
    int off = ((((T * 6 + g) << 10) + (r << 3) + (kp ^ rx)) << 3) + j;
    *reinterpret_cast<ushort2*>(&P[off]) = make_ushort2(e0, e1);
}

// ---- prep: normalize rows (fp32) + write split-bf16 tiled layout -----------
// mode 0 (z): k-layout [hi | lo | hi];  mode 1 (e): [hi | hi | lo]
__global__ __launch_bounds__(256) void k_prep(const float* __restrict__ src,
                                              float* __restrict__ dstN,
                                              ushort* __restrict__ dstP, int mode) {
    int t = threadIdx.x, w = t >> 6, lane = t & 63;
    int row = blockIdx.x * 4 + w;
    float2 v = *reinterpret_cast<const float2*>(&src[(size_t)row * DIM + lane * 2]);
    float ss = v.x * v.x + v.y * v.y;
#pragma unroll
    for (int off = 32; off; off >>= 1) ss += __shfl_xor(ss, off);
    float nrm = fmaxf(sqrtf(ss), 1e-12f);
    float a = v.x / nrm, b = v.y / nrm;
    *reinterpret_cast<float2*>(&dstN[(size_t)row * DIM + lane * 2]) = make_float2(a, b);
    ushort ha = f2bf(a), hb = f2bf(b);
    ushort la = f2bf(a - bf2f(ha)), lb = f2bf(b - bf2f(hb));
    int T = row >> 7, r = row & 127, rx = r & 7, d = lane * 2;
    bf_store2(dstP, T, r, rx, d, ha, hb);
    if (mode == 0) {
        bf_store2(dstP, T, r, rx, 128 + d, la, lb);
        bf_store2(dstP, T, r, rx, 256 + d, ha, hb);
    } else {
        bf_store2(dstP, T, r, rx, 128 + d, ha, hb);
        bf_store2(dstP, T, r, rx, 256 + d, la, lb);
    }
}

// ---- phase 1: MFMA GEMM + online (max, 2nd-max, argmax, sumexp) ------------
// grid 512: rg = b>>2 (128 row-groups of 128), slice = b&3 (2048 codes each)
__global__ __launch_bounds__(256, 2) void k_p1(const ushort* __restrict__ Zp,
                                               const ushort* __restrict__ Ep,
                                               float4* __restrict__ part) {
    __shared__ ushort Au[8192];  // 16KB: A tile (128 rows x 64 k), swizzled
    __shared__ ushort Bu[8192];  // 16KB: B tile (128 codes x 64 k)
    int t = threadIdx.x, lane = t & 63, w = t >> 6;
    int rg = blockIdx.x >> 2, slice = blockIdx.x & 3;
    int wm = w >> 1, wn = w & 1;           // wave grid 2x2 over 128x128
    int n15 = lane & 15, quad = lane >> 4;

    float sm[16], s2[16], sl[16];
    unsigned si[16];
#pragma unroll
    for (int s = 0; s < 16; ++s) { sm[s] = -1e30f; s2[s] = -1e30f; sl[s] = 0.f; si[s] = 0u; }

    for (int ch = 0; ch < 16; ++ch) {
        int ctile = slice * 16 + ch;
        f32x4 acc[4][4];
#pragma unroll
        for (int i = 0; i < 4; ++i)
#pragma unroll
            for (int j = 0; j < 4; ++j) acc[i][j] = (f32x4)0.0f;

        for (int g = 0; g < 6; ++g) {
            __syncthreads();
            const ushort* ga = Zp + (((size_t)rg * 6 + g) << 13);
            const ushort* gb = Ep + (((size_t)ctile * 6 + g) << 13);
#pragma unroll
            for (int rr = 0; rr < 4; ++rr) {
                int q = (rr * 256 + t) << 3;
                gld_lds16(ga + q, &Au[q]);
                gld_lds16(gb + q, &Bu[q]);
            }
            __syncthreads();
#pragma unroll
            for (int kl = 0; kl < 2; ++kl) {
                int kp = kl * 4 + quad;
                bf16x8 af[4], bfr[4];
#pragma unroll
                for (int ms = 0; ms < 4; ++ms) {
                    int r = wm * 64 + ms * 16 + n15;
                    af[ms] = *reinterpret_cast<const bf16x8*>(&Au[((r << 3) + (kp ^ (r & 7))) << 3]);
                }
#pragma unroll
                for (int ns = 0; ns < 4; ++ns) {
                    int c = wn * 64 + ns * 16 + n15;
                    bfr[ns] = *reinterpret_cast<const bf16x8*>(&Bu[((c << 3) + (kp ^ (c & 7))) << 3]);
                }
#pragma unroll
                for (int ms = 0; ms < 4; ++ms)
#pragma unroll
                    for (int ns = 0; ns < 4; ++ns)
                        acc[ms][ns] = MFMA16(af[ms], bfr[ns], acc[ms][ns]);
            }
        }
        // epilogue: per-lane online streams (codes strictly ascend per stream)
        unsigned cbase = slice * 2048 + ch * 128 + wn * 64 + n15;
#pragma unroll
        for (int ms = 0; ms < 4; ++ms)
#pragma unroll
            for (int reg = 0; reg < 4; ++reg) {
                int s = ms * 4 + reg;
                float m = sm[s], m2 = s2[s], l = sl[s];
                unsigned idx = si[s];
#pragma unroll
                for (int ns = 0; ns < 4; ++ns) {
                    float v = acc[ms][ns][reg];
                    unsigned code = cbase + ns * 16;
                    float d = v - m;
                    bool up = d > 0.f;
                    float e = __expf((up ? -d : d) * 10.f);
                    l = up ? fmaf(l, e, 1.0f) : (l + e);
                    m2 = up ? m : fmaxf(m2, v);
                    idx = up ? code : idx;
                    m = up ? v : m;
                }
                sm[s] = m; s2[s] = m2; sl[s] = l; si[s] = idx;
            }
    }
    // cross-lane merge over the 16-lane col group
#pragma unroll
    for (int ms = 0; ms < 4; ++ms)
#pragma unroll
        for (int reg = 0; reg < 4; ++reg) {
            int s = ms * 4 + reg;
            float m = sm[s], m2 = s2[s], l = sl[s];
            unsigned idx = si[s];
#pragma unroll
            for (int off = 1; off < 16; off <<= 1) {
                float om  = __shfl_xor(m, off);
                float om2 = __shfl_xor(m2, off);
                float ol  = __shfl_xor(l, off);
                unsigned oi = (unsigned)__shfl_xor((int)idx, off);
                m2 = fmaxf(fmaxf(m2, om2), fminf(m, om));
                float nm = fmaxf(m, om);
                l = l * __expf((m - nm) * 10.f) + ol * __expf((om - nm) * 10.f);
                bool take = (om > m) || (om == m && oi < idx);
                idx = take ? oi : idx;
                m = nm;
            }
            if (n15 == 0) {
                int row = rg * 128 + wm * 64 + ms * 16 + quad * 4 + reg;
                part[slice * N_ROWS + row] = make_float4(m, l, __uint_as_float(idx), m2);
            }
        }
}

// ---- merge 4 slice-partials per row; flag rows with tiny top-2 gap ---------
__global__ __launch_bounds__(256) void k_merge(const float4* __restrict__ part,
                                               float* __restrict__ m_out,
                                               float* __restrict__ linv_out,
                                               int* __restrict__ idx_out,
                                               int* __restrict__ flaglist,
                                               int* __restrict__ nflag) {
    int row = blockIdx.x * 256 + threadIdx.x;
    float m = -1e30f, m2 = -1e30f, l = 0.f;
    unsigned idx = 0u;
#pragma unroll
    for (int s = 0; s < 4; ++s) {
        float4 p = part[s * N_ROWS + row];
        float om = p.x, ol = p.y, om2 = p.w;
        unsigned oi = __float_as_uint(p.z);
        m2 = fmaxf(fmaxf(m2, om2), fminf(m, om));
        float nm = fmaxf(m, om);
        l = l * __expf((m - nm) * 10.f) + ol * __expf((om - nm) * 10.f);
        bool take = (om > m) || (om == m && oi < idx);
        idx = take ? oi : idx;
        m = nm;
    }
    m_out[row] = m;
    linv_out[row] = 1.0f / l;
    idx_out[row] = (int)idx;
    if (m - m2 < EPSF) {
        int pos = atomicAdd(nflag, 1);
        flaglist[pos] = row;
    }
}

// ---- fp64 exact re-argmax for flagged rows ---------------------------------
// grid 512 fixed; block b handles flagged rows b, b+512, ... (block owns row)
__global__ __launch_bounds__(256) void k_refine(const float* __restrict__ zN,
                                                const float* __restrict__ eN,
                                                const int* __restrict__ flaglist,
                                                const int* __restrict__ nflag,
                                                int* __restrict__ idx) {
    int nf = *nflag;
    if (nf > N_ROWS) nf = N_ROWS;
    int t = threadIdx.x, w = t >> 6, lane = t & 63;
    __shared__ double wbest[4];
    __shared__ int wbi[4];
    for (int fi = blockIdx.x; fi < nf; fi += 512) {
        int row = flaglist[fi];
        float2 zv = *reinterpret_cast<const float2*>(&zN[(size_t)row * DIM + lane * 2]);
        double z0 = (double)zv.x, z1 = (double)zv.y;
        double best = -1e300;
        int bi = 0x7FFFFFFF;
        for (int j = 0; j < 2048; j += 2) {
            int c0 = j * 4 + w, c1 = (j + 1) * 4 + w;
            float2 e0 = *reinterpret_cast<const float2*>(&eN[(size_t)c0 * DIM + lane * 2]);
            float2 e1 = *reinterpret_cast<const float2*>(&eN[(size_t)c1 * DIM + lane * 2]);
            double s0 = z0 * (double)e0.x + z1 * (double)e0.y;
            double s1 = z0 * (double)e1.x + z1 * (double)e1.y;
#pragma unroll
            for (int off = 1; off < 64; off <<= 1) {
                s0 += __shfl_xor(s0, off);
                s1 += __shfl_xor(s1, off);
            }
            if (s0 > best || (s0 == best && c0 < bi)) { best = s0; bi = c0; }
            if (s1 > best || (s1 == best && c1 < bi)) { best = s1; bi = c1; }
        }
        if (lane == 0) { wbest[w] = best; wbi[w] = bi; }
        __syncthreads();
        if (t == 0) {
            for (int ww = 1; ww < 4; ++ww)
                if (wbest[ww] > best || (wbest[ww] == best && wbi[ww] < bi)) {
                    best = wbest[ww]; bi = wbi[ww];
                }
            idx[row] = bi;
        }
        __syncthreads();
    }
}

__global__ void k_counts(const int* __restrict__ idx, unsigned int* __restrict__ counts) {
    int i = blockIdx.x * 256 + threadIdx.x;
    atomicAdd(&counts[idx[i]], 1u);
}

// ---- phase 2: rotated GEMM (codes = M); P_sum[k] += exp((s-m)*10)*linv -----
// grid 512: cg = b>>3 (64 code-groups of 128), rs = b&7 (2048 rows each)
__global__ __launch_bounds__(256, 2) void k_p2(const ushort* __restrict__ Zp,
                                               const ushort* __restrict__ Ep,
                                               const float* __restrict__ m_in,
                                               const float* __restrict__ linv_in,
                                               float* __restrict__ P_sum) {
    __shared__ ushort Au[8192];  // codes tile
    __shared__ ushort Bu[8192];  // rows tile
    int t = threadIdx.x, lane = t & 63, w = t >> 6;
    int cg = blockIdx.x >> 3, rs = blockIdx.x & 7;
    int wm = w >> 1, wn = w & 1;
    int n15 = lane & 15, quad = lane >> 4;

    float pacc[16];
#pragma unroll
    for (int s = 0; s < 16; ++s) pacc[s] = 0.f;

    for (int ch = 0; ch < 16; ++ch) {
        int rtile = rs * 16 + ch;
        f32x4 acc[4][4];
#pragma unroll
        for (int i = 0; i < 4; ++i)
#pragma unroll
            for (int j = 0; j < 4; ++j) acc[i][j] = (f32x4)0.0f;

        for (int g = 0; g < 6; ++g) {
            __syncthreads();
            const ushort* ga = Ep + (((size_t)cg * 6 + g) << 13);
            const ushort* gb = Zp + (((size_t)rtile * 6 + g) << 13);
#pragma unroll
            for (int rr = 0; rr < 4; ++rr) {
                int q = (rr * 256 + t) << 3;
                gld_lds16(ga + q, &Au[q]);
                gld_lds16(gb + q, &Bu[q]);
            }
            __syncthreads();
#pragma unroll
            for (int kl = 0; kl < 2; ++kl) {
                int kp = kl * 4 + quad;
                bf16x8 af[4], bfr[4];
#pragma unroll
                for (int ms = 0; ms < 4; ++ms) {
                    int r = wm * 64 + ms * 16 + n15;
                    af[ms] = *reinterpret_cast<const bf16x8*>(&Au[((r << 3) + (kp ^ (r & 7))) << 3]);
                }
#pragma unroll
                for (int ns = 0; ns < 4; ++ns) {
                    int c = wn * 64 + ns * 16 + n15;
                    bfr[ns] = *reinterpret_cast<const bf16x8*>(&Bu[((c << 3) + (kp ^ (c & 7))) << 3]);
                }
#pragma unroll
                for (int ms = 0; ms < 4; ++ms)
#pragma unroll
                    for (int ns = 0; ns < 4; ++ns)
                        acc[ms][ns] = MFMA16(af[ms], bfr[ns], acc[ms][ns]);
            }
        }
        int rbase = rs * 2048 + ch * 128 + wn * 64 + n15;
        float mr[4], li[4];
#pragma unroll
        for (int ns = 0; ns < 4; ++ns) {
            mr[ns] = m_in[rbase + ns * 16];
            li[ns] = linv_in[rbase + ns * 16];
        }
#pragma unroll
        for (int ms = 0; ms < 4; ++ms)
#pragma unroll
            for (int reg = 0; reg < 4; ++reg) {
                int s = ms * 4 + reg;
                float p = pacc[s];
#pragma unroll
                for (int ns = 0; ns < 4; ++ns)
                    p = fmaf(__expf((acc[ms][ns][reg] - mr[ns]) * 10.f), li[ns], p);
                pacc[s] = p;
            }
    }
#pragma unroll
    for (int s = 0; s < 16; ++s) {
#pragma unroll
        for (int off = 1; off < 16; off <<= 1) pacc[s] += __shfl_xor(pacc[s], off);
    }
    if (n15 == 0) {
#pragma unroll
        for (int ms = 0; ms < 4; ++ms)
#pragma unroll
            for (int reg = 0; reg < 4; ++reg)
                atomicAdd(&P_sum[cg * 128 + wm * 64 + ms * 16 + quad * 4 + reg],
                          pacc[ms * 4 + reg]);
    }
}

// ---- gather z_q_st + commit-loss partial -----------------------------------
__global__ __launch_bounds__(256) void k_gather(const float* __restrict__ z,
                                                const float* __restrict__ W,
                                                const int* __restrict__ idx,
                                                float* __restrict__ out,
                                                float* __restrict__ mse) {
    int v = blockIdx.x * 256 + threadIdx.x;
    int row = v >> 5;
    int id = idx[row];
    float4 q = *reinterpret_cast<const float4*>(&W[(size_t)id * DIM + (v & 31) * 4]);
    float4 zz = *reinterpret_cast<const float4*>(&z[(size_t)v * 4]);
    float dx = q.x - zz.x, dy = q.y - zz.y, dz = q.z - zz.z, dw = q.w - zz.w;
    *reinterpret_cast<float4*>(&out[(size_t)v * 4]) = q;
    float e = dx * dx + dy * dy + dz * dz + dw * dw;
#pragma unroll
    for (int off = 1; off < 64; off <<= 1) e += __shfl_xor(e, off);
    __shared__ float red[4];
    int lane = threadIdx.x & 63, wv = threadIdx.x >> 6;
    if (lane == 0) red[wv] = e;
    __syncthreads();
    if (threadIdx.x == 0) atomicAdd(mse, red[0] + red[1] + red[2] + red[3]);
}

// ---- finalize scalars -------------------------------------------------------
__global__ __launch_bounds__(256) void k_finalize(const unsigned int* __restrict__ counts,
                                                  const float* __restrict__ P_sum,
                                                  const float* __restrict__ mse,
                                                  float* __restrict__ out) {
    int t = threadIdx.x;
    float s1 = 0.f, s2 = 0.f;
    for (int k = t; k < K_CODES; k += 256) {
        float em = (float)counts[k] * (1.0f / 16384.0f);
        s1 += em * logf(em + 1e-8f);
        float p = P_sum[k] * (1.0f / 16384.0f) + 1e-8f;
        s2 += p * logf(p);
    }
#pragma unroll
    for (int off = 1; off < 64; off <<= 1) {
        s1 += __shfl_xor(s1, off);
        s2 += __shfl_xor(s2, off);
    }
    __shared__ float r1[4], r2[4];
    int lane = t & 63, wv = t >> 6;
    if (lane == 0) { r1[wv] = s1; r2[wv] = s2; }
    __syncthreads();
    if (t == 0) {
        float S1 = r1[0] + r1[1] + r1[2] + r1[3];
        float S2 = r2[0] + r2[1] + r2[2] + r2[3];
        out[2097152] = 1.25f * mse[0] * (1.0f / 2097152.0f);
        out[2097153] = expf(-S1);
        out[2097154] = -S2;
    }
}

extern "C" void kernel_launch(void* const* d_in, const int* in_sizes, int n_in,
                              void* d_out, int out_size, void* d_ws, size_t ws_size,
                              hipStream_t stream) {
    (void)in_sizes; (void)n_in; (void)out_size; (void)ws_size;
    const float* z = (const float*)d_in[0];
    const float* W = (const float*)d_in[1];
    float* ws = (float*)d_ws;
    float* eN = ws + OFF_EN;
    float* zN = ws + OFF_ZN;
    ushort* Ep = (ushort*)(ws + OFF_EP);
    ushort* Zp = (ushort*)(ws + OFF_ZP);
    float4* part = (float4*)(ws + OFF_PART);
    float* m = ws + OFF_M;
    float* linv = ws + OFF_LINV;
    int* idx = (int*)(ws + OFF_IDX);
    int* flaglist = (int*)(ws + OFF_FLAGLIST);
    unsigned int* counts = (unsigned int*)(ws + OFF_CNT);
    float* P = ws + OFF_P;
    float* mse = ws + OFF_MSE;
    int* nflag = (int*)(ws + OFF_NFLAG);
    float* out = (float*)d_out;

    hipMemsetAsync(ws + OFF_CNT, 0, MEMSET_BYTES, stream);
    k_prep<<<N_ROWS / 4, 256, 0, stream>>>(z, zN, Zp, 0);
    k_prep<<<K_CODES / 4, 256, 0, stream>>>(W, eN, Ep, 1);
    k_p1<<<512, 256, 0, stream>>>(Zp, Ep, part);
    k_merge<<<N_ROWS / 256, 256, 0, stream>>>(part, m, linv, idx, flaglist, nflag);
    k_refine<<<512, 256, 0, stream>>>(zN, eN, flaglist, nflag, idx);
    k_counts<<<N_ROWS / 256, 256, 0, stream>>>(idx, counts);
    k_p2<<<512, 256, 0, stream>>>(Zp, Ep, m, linv, P);
    k_gather<<<(N_ROWS * DIM / 4) / 256, 256, 0, stream>>>(z, W, idx, out, mse);
    k_finalize<<<1, 256, 0, stream>>>(counts, P, mse, out);
}

// Round 4
// 436.673 us; speedup vs baseline: 5.1160x; 2.2085x over previous
//
#include <hip/hip_runtime.h>
#include <hip/hip_bf16.h>
#include <math.h>

#define N_ROWS 16384
#define DIM 128
#define K_CODES 8192
#define EPSF 7e-5f            // top-2 gap flag threshold (split-bf16 err ~1e-6)

// ---- workspace layout (float offsets) --------------------------------------
#define OFF_EN       0u          // eN fp32: 8192*128            = 1,048,576 f
#define OFF_ZN       1048576u    // zN fp32: 16384*128           = 2,097,152 f
#define OFF_EP       3145728u    // Ep bf16: 8192*384  (1,572,864 f)
#define OFF_ZP       4718592u    // Zp bf16: 16384*384 (3,145,728 f)
#define OFF_PART     7864320u    // phase1 partials: 4*16384 float4 = 262,144 f
#define OFF_M        8126464u    // 16384
#define OFF_LINV     8142848u    // 16384
#define OFF_IDX      8159232u    // 16384 int
#define OFF_FLAGLIST 8175616u    // 16384 int
#define OFF_CNT      8192000u    // 8192 u32   <-- memset region starts here
#define OFF_P        8200192u    // 8192 f
#define OFF_MSE      8208384u    // 1
#define OFF_NFLAG    8208385u    // 1 int
#define OFF_REFBUF   8208386u    // 16384 u64 (byte offset divisible by 8)
#define MEMSET_BYTES 196616u     // counts + P + mse + nflag + refbuf

typedef __bf16 bf16x8 __attribute__((ext_vector_type(8)));
typedef float  f32x4  __attribute__((ext_vector_type(4)));
#define MFMA16(a, b, c) __builtin_amdgcn_mfma_f32_16x16x32_bf16(a, b, c, 0, 0, 0)

__device__ __forceinline__ void gld_lds16(const ushort* g, ushort* l) {
    __builtin_amdgcn_global_load_lds(
        (const __attribute__((address_space(1))) unsigned int*)g,
        (__attribute__((address_space(3))) unsigned int*)l, 16, 0, 0);
}

__device__ __forceinline__ ushort f2bf(float x) {
    __hip_bfloat16 b = __float2bfloat16(x);
    return *reinterpret_cast<ushort*>(&b);
}
__device__ __forceinline__ float bf2f(ushort u) {
    __hip_bfloat16 b = *reinterpret_cast<__hip_bfloat16*>(&u);
    return __bfloat162float(b);
}

// tiled+swizzled bf16 store: element (tile row r, k) of tile T ->
// chunk q = r*8 + ((k>>3 & 7) ^ (r&7)) within kgroup g=k>>6; 16B chunks.
__device__ __forceinline__ void bf_store2(ushort* __restrict__ P, int T, int r,
                                          int rx, int k, ushort e0, ushort e1) {
    int g = k >> 6, kp = (k >> 3) & 7, j = k & 7;
    int off = ((((T * 6 + g) << 10) + (r << 3) + (kp ^ rx)) << 3) + j;
    *reinterpret_cast<ushort2*>(&P[off]) = make_ushort2(e0, e1);
}

// ---- prep: normalize rows (fp32) + write split-bf16 tiled layout -----------
// mode 0 (z): k-layout [hi | lo | hi];  mode 1 (e): [hi | hi | lo]
__global__ __launch_bounds__(256) void k_prep(const float* __restrict__ src,
                                              float* __restrict__ dstN,
                                              ushort* __restrict__ dstP, int mode) {
    int t = threadIdx.x, w = t >> 6, lane = t & 63;
    int row = blockIdx.x * 4 + w;
    float2 v = *reinterpret_cast<const float2*>(&src[(size_t)row * DIM + lane * 2]);
    float ss = v.x * v.x + v.y * v.y;
#pragma unroll
    for (int off = 32; off; off >>= 1) ss += __shfl_xor(ss, off);
    float nrm = fmaxf(sqrtf(ss), 1e-12f);
    float a = v.x / nrm, b = v.y / nrm;
    *reinterpret_cast<float2*>(&dstN[(size_t)row * DIM + lane * 2]) = make_float2(a, b);
    ushort ha = f2bf(a), hb = f2bf(b);
    ushort la = f2bf(a - bf2f(ha)), lb = f2bf(b - bf2f(hb));
    int T = row >> 7, r = row & 127, rx = r & 7, d = lane * 2;
    bf_store2(dstP, T, r, rx, d, ha, hb);
    if (mode == 0) {
        bf_store2(dstP, T, r, rx, 128 + d, la, lb);
        bf_store2(dstP, T, r, rx, 256 + d, ha, hb);
    } else {
        bf_store2(dstP, T, r, rx, 128 + d, ha, hb);
        bf_store2(dstP, T, r, rx, 256 + d, la, lb);
    }
}

// ---- phase 1: MFMA GEMM + online (max, 2nd-max, argmax, sumexp) ------------
// grid 512: rg = b>>2 (128 row-groups of 128), slice = b&3 (2048 codes each)
__global__ __launch_bounds__(256, 2) void k_p1(const ushort* __restrict__ Zp,
                                               const ushort* __restrict__ Ep,
                                               float4* __restrict__ part) {
    __shared__ ushort Au[8192];  // 16KB: A tile (128 rows x 64 k), swizzled
    __shared__ ushort Bu[8192];  // 16KB: B tile (128 codes x 64 k)
    int t = threadIdx.x, lane = t & 63, w = t >> 6;
    int rg = blockIdx.x >> 2, slice = blockIdx.x & 3;
    int wm = w >> 1, wn = w & 1;           // wave grid 2x2 over 128x128
    int n15 = lane & 15, quad = lane >> 4;

    float sm[16], s2[16], sl[16];
    unsigned si[16];
#pragma unroll
    for (int s = 0; s < 16; ++s) { sm[s] = -1e30f; s2[s] = -1e30f; sl[s] = 0.f; si[s] = 0u; }

    for (int ch = 0; ch < 16; ++ch) {
        int ctile = slice * 16 + ch;
        f32x4 acc[4][4];
#pragma unroll
        for (int i = 0; i < 4; ++i)
#pragma unroll
            for (int j = 0; j < 4; ++j) acc[i][j] = (f32x4)0.0f;

        for (int g = 0; g < 6; ++g) {
            __syncthreads();
            const ushort* ga = Zp + (((size_t)rg * 6 + g) << 13);
            const ushort* gb = Ep + (((size_t)ctile * 6 + g) << 13);
#pragma unroll
            for (int rr = 0; rr < 4; ++rr) {
                int q = (rr * 256 + t) << 3;
                gld_lds16(ga + q, &Au[q]);
                gld_lds16(gb + q, &Bu[q]);
            }
            __syncthreads();
#pragma unroll
            for (int kl = 0; kl < 2; ++kl) {
                int kp = kl * 4 + quad;
                bf16x8 af[4], bfr[4];
#pragma unroll
                for (int ms = 0; ms < 4; ++ms) {
                    int r = wm * 64 + ms * 16 + n15;
                    af[ms] = *reinterpret_cast<const bf16x8*>(&Au[((r << 3) + (kp ^ (r & 7))) << 3]);
                }
#pragma unroll
                for (int ns = 0; ns < 4; ++ns) {
                    int c = wn * 64 + ns * 16 + n15;
                    bfr[ns] = *reinterpret_cast<const bf16x8*>(&Bu[((c << 3) + (kp ^ (c & 7))) << 3]);
                }
#pragma unroll
                for (int ms = 0; ms < 4; ++ms)
#pragma unroll
                    for (int ns = 0; ns < 4; ++ns)
                        acc[ms][ns] = MFMA16(af[ms], bfr[ns], acc[ms][ns]);
            }
        }
        // epilogue: per-lane online streams (codes strictly ascend per stream)
        unsigned cbase = slice * 2048 + ch * 128 + wn * 64 + n15;
#pragma unroll
        for (int ms = 0; ms < 4; ++ms)
#pragma unroll
            for (int reg = 0; reg < 4; ++reg) {
                int s = ms * 4 + reg;
                float m = sm[s], m2 = s2[s], l = sl[s];
                unsigned idx = si[s];
#pragma unroll
                for (int ns = 0; ns < 4; ++ns) {
                    float v = acc[ms][ns][reg];
                    unsigned code = cbase + ns * 16;
                    float d = v - m;
                    bool up = d > 0.f;
                    float e = __expf((up ? -d : d) * 10.f);
                    l = up ? fmaf(l, e, 1.0f) : (l + e);
                    m2 = up ? m : fmaxf(m2, v);
                    idx = up ? code : idx;
                    m = up ? v : m;
                }
                sm[s] = m; s2[s] = m2; sl[s] = l; si[s] = idx;
            }
    }
    // cross-lane merge over the 16-lane col group
#pragma unroll
    for (int ms = 0; ms < 4; ++ms)
#pragma unroll
        for (int reg = 0; reg < 4; ++reg) {
            int s = ms * 4 + reg;
            float m = sm[s], m2 = s2[s], l = sl[s];
            unsigned idx = si[s];
#pragma unroll
            for (int off = 1; off < 16; off <<= 1) {
                float om  = __shfl_xor(m, off);
                float om2 = __shfl_xor(m2, off);
                float ol  = __shfl_xor(l, off);
                unsigned oi = (unsigned)__shfl_xor((int)idx, off);
                m2 = fmaxf(fmaxf(m2, om2), fminf(m, om));
                float nm = fmaxf(m, om);
                l = l * __expf((m - nm) * 10.f) + ol * __expf((om - nm) * 10.f);
                bool take = (om > m) || (om == m && oi < idx);
                idx = take ? oi : idx;
                m = nm;
            }
            if (n15 == 0) {
                int row = rg * 128 + wm * 64 + ms * 16 + quad * 4 + reg;
                part[slice * N_ROWS + row] = make_float4(m, l, __uint_as_float(idx), m2);
            }
        }
}

// ---- merge 4 slice-partials per row; flag rows with tiny top-2 gap ---------
__global__ __launch_bounds__(256) void k_merge(const float4* __restrict__ part,
                                               float* __restrict__ m_out,
                                               float* __restrict__ linv_out,
                                               int* __restrict__ idx_out,
                                               int* __restrict__ flaglist,
                                               int* __restrict__ nflag) {
    int row = blockIdx.x * 256 + threadIdx.x;
    float m = -1e30f, m2 = -1e30f, l = 0.f;
    unsigned idx = 0u;
#pragma unroll
    for (int s = 0; s < 4; ++s) {
        float4 p = part[s * N_ROWS + row];
        float om = p.x, ol = p.y, om2 = p.w;
        unsigned oi = __float_as_uint(p.z);
        m2 = fmaxf(fmaxf(m2, om2), fminf(m, om));
        float nm = fmaxf(m, om);
        l = l * __expf((m - nm) * 10.f) + ol * __expf((om - nm) * 10.f);
        bool take = (om > m) || (om == m && oi < idx);
        idx = take ? oi : idx;
        m = nm;
    }
    m_out[row] = m;
    linv_out[row] = 1.0f / l;
    idx_out[row] = (int)idx;
    if (m - m2 < EPSF) {
        int pos = atomicAdd(nflag, 1);
        flaglist[pos] = row;
    }
}

// ---- fp64 exact re-argmax for flagged rows (parallel, no inner shuffles) ---
// grid 4096: fi = b>>3 (flagged row, grid-strided), csl = b&7 (1024 codes).
// Each thread: 4 independent fp64 dot chains; one wave-reduce at the end;
// 64-bit atomicMax key = monotone(double score) top-51b | (8191-code).
__global__ __launch_bounds__(256) void k_refine(const float* __restrict__ zN,
                                                const float* __restrict__ eN,
                                                const int* __restrict__ flaglist,
                                                const int* __restrict__ nflag,
                                                unsigned long long* __restrict__ refbuf) {
    int nf = *nflag;
    if (nf > N_ROWS) nf = N_ROWS;
    int csl = blockIdx.x & 7;
    int t = threadIdx.x;
    __shared__ float zl[DIM];
    for (int fi = blockIdx.x >> 3; fi < nf; fi += 512) {
        int row = flaglist[fi];
        __syncthreads();
        if (t < DIM) zl[t] = zN[(size_t)row * DIM + t];
        __syncthreads();
        double best = -1e300;
        int bc = 0x7FFFFFFF;
#pragma unroll
        for (int j = 0; j < 4; ++j) {
            int c = csl * 1024 + j * 256 + t;
            const float* e = &eN[(size_t)c * DIM];
            double s = 0.0;
#pragma unroll 8
            for (int d = 0; d < DIM; ++d) s += (double)zl[d] * (double)e[d];
            if (s > best) { best = s; bc = c; }   // codes ascend with j: keeps first
        }
#pragma unroll
        for (int off = 1; off < 64; off <<= 1) {
            double ob = __shfl_xor(best, off);
            int oc = __shfl_xor(bc, off);
            if (ob > best || (ob == best && oc < bc)) { best = ob; bc = oc; }
        }
        if ((t & 63) == 0) {
            unsigned long long u = (unsigned long long)__double_as_longlong(best);
            u = (u & 0x8000000000000000ull) ? ~u : (u | 0x8000000000000000ull);
            unsigned long long key = (u & ~0x1FFFull) | (unsigned long long)(8191 - bc);
            atomicMax(&refbuf[row], key);
        }
    }
}

__global__ __launch_bounds__(256) void k_fixidx(const int* __restrict__ flaglist,
                                                const int* __restrict__ nflag,
                                                const unsigned long long* __restrict__ refbuf,
                                                int* __restrict__ idx) {
    int i = blockIdx.x * 256 + threadIdx.x;
    int nf = *nflag;
    if (nf > N_ROWS) nf = N_ROWS;
    if (i < nf) {
        int row = flaglist[i];
        idx[row] = 8191 - (int)(refbuf[row] & 0x1FFFull);
    }
}

__global__ void k_counts(const int* __restrict__ idx, unsigned int* __restrict__ counts) {
    int i = blockIdx.x * 256 + threadIdx.x;
    atomicAdd(&counts[idx[i]], 1u);
}

// ---- phase 2: rotated GEMM (codes = M); P_sum[k] += exp((s-m)*10)*linv -----
// grid 512: cg = b>>3 (64 code-groups of 128), rs = b&7 (2048 rows each)
__global__ __launch_bounds__(256, 2) void k_p2(const ushort* __restrict__ Zp,
                                               const ushort* __restrict__ Ep,
                                               const float* __restrict__ m_in,
                                               const float* __restrict__ linv_in,
                                               float* __restrict__ P_sum) {
    __shared__ ushort Au[8192];  // codes tile
    __shared__ ushort Bu[8192];  // rows tile
    int t = threadIdx.x, lane = t & 63, w = t >> 6;
    int cg = blockIdx.x >> 3, rs = blockIdx.x & 7;
    int wm = w >> 1, wn = w & 1;
    int n15 = lane & 15, quad = lane >> 4;

    float pacc[16];
#pragma unroll
    for (int s = 0; s < 16; ++s) pacc[s] = 0.f;

    for (int ch = 0; ch < 16; ++ch) {
        int rtile = rs * 16 + ch;
        f32x4 acc[4][4];
#pragma unroll
        for (int i = 0; i < 4; ++i)
#pragma unroll
            for (int j = 0; j < 4; ++j) acc[i][j] = (f32x4)0.0f;

        for (int g = 0; g < 6; ++g) {
            __syncthreads();
            const ushort* ga = Ep + (((size_t)cg * 6 + g) << 13);
            const ushort* gb = Zp + (((size_t)rtile * 6 + g) << 13);
#pragma unroll
            for (int rr = 0; rr < 4; ++rr) {
                int q = (rr * 256 + t) << 3;
                gld_lds16(ga + q, &Au[q]);
                gld_lds16(gb + q, &Bu[q]);
            }
            __syncthreads();
#pragma unroll
            for (int kl = 0; kl < 2; ++kl) {
                int kp = kl * 4 + quad;
                bf16x8 af[4], bfr[4];
#pragma unroll
                for (int ms = 0; ms < 4; ++ms) {
                    int r = wm * 64 + ms * 16 + n15;
                    af[ms] = *reinterpret_cast<const bf16x8*>(&Au[((r << 3) + (kp ^ (r & 7))) << 3]);
                }
#pragma unroll
                for (int ns = 0; ns < 4; ++ns) {
                    int c = wn * 64 + ns * 16 + n15;
                    bfr[ns] = *reinterpret_cast<const bf16x8*>(&Bu[((c << 3) + (kp ^ (c & 7))) << 3]);
                }
#pragma unroll
                for (int ms = 0; ms < 4; ++ms)
#pragma unroll
                    for (int ns = 0; ns < 4; ++ns)
                        acc[ms][ns] = MFMA16(af[ms], bfr[ns], acc[ms][ns]);
            }
        }
        int rbase = rs * 2048 + ch * 128 + wn * 64 + n15;
        float mr[4], li[4];
#pragma unroll
        for (int ns = 0; ns < 4; ++ns) {
            mr[ns] = m_in[rbase + ns * 16];
            li[ns] = linv_in[rbase + ns * 16];
        }
#pragma unroll
        for (int ms = 0; ms < 4; ++ms)
#pragma unroll
            for (int reg = 0; reg < 4; ++reg) {
                int s = ms * 4 + reg;
                float p = pacc[s];
#pragma unroll
                for (int ns = 0; ns < 4; ++ns)
                    p = fmaf(__expf((acc[ms][ns][reg] - mr[ns]) * 10.f), li[ns], p);
                pacc[s] = p;
            }
    }
#pragma unroll
    for (int s = 0; s < 16; ++s) {
#pragma unroll
        for (int off = 1; off < 16; off <<= 1) pacc[s] += __shfl_xor(pacc[s], off);
    }
    if (n15 == 0) {
#pragma unroll
        for (int ms = 0; ms < 4; ++ms)
#pragma unroll
            for (int reg = 0; reg < 4; ++reg)
                atomicAdd(&P_sum[cg * 128 + wm * 64 + ms * 16 + quad * 4 + reg],
                          pacc[ms * 4 + reg]);
    }
}

// ---- gather z_q_st + commit-loss partial -----------------------------------
__global__ __launch_bounds__(256) void k_gather(const float* __restrict__ z,
                                                const float* __restrict__ W,
                                                const int* __restrict__ idx,
                                                float* __restrict__ out,
                                                float* __restrict__ mse) {
    int v = blockIdx.x * 256 + threadIdx.x;
    int row = v >> 5;
    int id = idx[row];
    float4 q = *reinterpret_cast<const float4*>(&W[(size_t)id * DIM + (v & 31) * 4]);
    float4 zz = *reinterpret_cast<const float4*>(&z[(size_t)v * 4]);
    float dx = q.x - zz.x, dy = q.y - zz.y, dz = q.z - zz.z, dw = q.w - zz.w;
    *reinterpret_cast<float4*>(&out[(size_t)v * 4]) = q;
    float e = dx * dx + dy * dy + dz * dz + dw * dw;
#pragma unroll
    for (int off = 1; off < 64; off <<= 1) e += __shfl_xor(e, off);
    __shared__ float red[4];
    int lane = threadIdx.x & 63, wv = threadIdx.x >> 6;
    if (lane == 0) red[wv] = e;
    __syncthreads();
    if (threadIdx.x == 0) atomicAdd(mse, red[0] + red[1] + red[2] + red[3]);
}

// ---- finalize scalars -------------------------------------------------------
__global__ __launch_bounds__(256) void k_finalize(const unsigned int* __restrict__ counts,
                                                  const float* __restrict__ P_sum,
                                                  const float* __restrict__ mse,
                                                  float* __restrict__ out) {
    int t = threadIdx.x;
    float s1 = 0.f, s2 = 0.f;
    for (int k = t; k < K_CODES; k += 256) {
        float em = (float)counts[k] * (1.0f / 16384.0f);
        s1 += em * logf(em + 1e-8f);
        float p = P_sum[k] * (1.0f / 16384.0f) + 1e-8f;
        s2 += p * logf(p);
    }
#pragma unroll
    for (int off = 1; off < 64; off <<= 1) {
        s1 += __shfl_xor(s1, off);
        s2 += __shfl_xor(s2, off);
    }
    __shared__ float r1[4], r2[4];
    int lane = t & 63, wv = t >> 6;
    if (lane == 0) { r1[wv] = s1; r2[wv] = s2; }
    __syncthreads();
    if (t == 0) {
        float S1 = r1[0] + r1[1] + r1[2] + r1[3];
        float S2 = r2[0] + r2[1] + r2[2] + r2[3];
        out[2097152] = 1.25f * mse[0] * (1.0f / 2097152.0f);
        out[2097153] = expf(-S1);
        out[2097154] = -S2;
    }
}

extern "C" void kernel_launch(void* const* d_in, const int* in_sizes, int n_in,
                              void* d_out, int out_size, void* d_ws, size_t ws_size,
                              hipStream_t stream) {
    (void)in_sizes; (void)n_in; (void)out_size; (void)ws_size;
    const float* z = (const float*)d_in[0];
    const float* W = (const float*)d_in[1];
    float* ws = (float*)d_ws;
    float* eN = ws + OFF_EN;
    float* zN = ws + OFF_ZN;
    ushort* Ep = (ushort*)(ws + OFF_EP);
    ushort* Zp = (ushort*)(ws + OFF_ZP);
    float4* part = (float4*)(ws + OFF_PART);
    float* m = ws + OFF_M;
    float* linv = ws + OFF_LINV;
    int* idx = (int*)(ws + OFF_IDX);
    int* flaglist = (int*)(ws + OFF_FLAGLIST);
    unsigned int* counts = (unsigned int*)(ws + OFF_CNT);
    float* P = ws + OFF_P;
    float* mse = ws + OFF_MSE;
    int* nflag = (int*)(ws + OFF_NFLAG);
    unsigned long long* refbuf = (unsigned long long*)(ws + OFF_REFBUF);
    float* out = (float*)d_out;

    hipMemsetAsync(ws + OFF_CNT, 0, MEMSET_BYTES, stream);
    k_prep<<<N_ROWS / 4, 256, 0, stream>>>(z, zN, Zp, 0);
    k_prep<<<K_CODES / 4, 256, 0, stream>>>(W, eN, Ep, 1);
    k_p1<<<512, 256, 0, stream>>>(Zp, Ep, part);
    k_merge<<<N_ROWS / 256, 256, 0, stream>>>(part, m, linv, idx, flaglist, nflag);
    k_refine<<<4096, 256, 0, stream>>>(zN, eN, flaglist, nflag, refbuf);
    k_fixidx<<<64, 256, 0, stream>>>(flaglist, nflag, refbuf, idx);
    k_counts<<<N_ROWS / 256, 256, 0, stream>>>(idx, counts);
    k_p2<<<512, 256, 0, stream>>>(Zp, Ep, m, linv, P);
    k_gather<<<(N_ROWS * DIM / 4) / 256, 256, 0, stream>>>(z, W, idx, out, mse);
    k_finalize<<<1, 256, 0, stream>>>(counts, P, mse, out);
}

// Round 5
// 347.743 us; speedup vs baseline: 6.4243x; 1.2557x over previous
//
#include <hip/hip_runtime.h>
#include <hip/hip_bf16.h>
#include <math.h>

#define N_ROWS 16384
#define DIM 128
#define K_CODES 8192
#define EPSF 7e-5f            // top-2 gap flag threshold (split-bf16 err ~1e-5)

// ---- workspace layout (float offsets) --------------------------------------
#define OFF_EN       0u          // eN fp32: 8192*128
#define OFF_ZN       1048576u    // zN fp32: 16384*128
#define OFF_EP       3145728u    // Ep bf16: 8192*384
#define OFF_ZP       4718592u    // Zp bf16: 16384*384
#define OFF_PART     7864320u    // phase1 partials: 4*16384 float4
#define OFF_M        8126464u    // (unused now)
#define OFF_LINV     8142848u    // 16384
#define OFF_IDX      8159232u    // 16384 int
#define OFF_FLAGLIST 8175616u    // 16384 int
#define OFF_CNT      8192000u    // 8192 u32   <-- memset region starts here
#define OFF_P        8200192u    // 8192 f
#define OFF_MSE      8208384u    // 1
#define OFF_NFLAG    8208385u    // 1 int
#define OFF_REFBUF   8208386u    // 16384 u64
#define MEMSET_BYTES 196616u     // counts + P + mse + nflag + refbuf

typedef __bf16 bf16x8 __attribute__((ext_vector_type(8)));
typedef float  f32x4  __attribute__((ext_vector_type(4)));
#define MFMA16(a, b, c) __builtin_amdgcn_mfma_f32_16x16x32_bf16(a, b, c, 0, 0, 0)

__device__ __forceinline__ void gld_lds16(const ushort* g, ushort* l) {
    __builtin_amdgcn_global_load_lds(
        (const __attribute__((address_space(1))) unsigned int*)g,
        (__attribute__((address_space(3))) unsigned int*)l, 16, 0, 0);
}

__device__ __forceinline__ ushort f2bf(float x) {
    __hip_bfloat16 b = __float2bfloat16(x);
    return *reinterpret_cast<ushort*>(&b);
}
__device__ __forceinline__ float bf2f(ushort u) {
    __hip_bfloat16 b = *reinterpret_cast<__hip_bfloat16*>(&u);
    return __bfloat162float(b);
}

// tiled+swizzled bf16 store: element (tile row r, k) of tile T ->
// chunk = r*8 + ((k>>3 & 7) ^ (r&7)) within kgroup g=k>>6; 16B chunks.
__device__ __forceinline__ void bf_store2(ushort* __restrict__ P, int T, int r,
                                          int rx, int k, ushort e0, ushort e1) {
    int g = k >> 6, kp = (k >> 3) & 7, j = k & 7;
    int off = ((((T * 6 + g) << 10) + (r << 3) + (kp ^ rx)) << 3) + j;
    *reinterpret_cast<ushort2*>(&P[off]) = make_ushort2(e0, e1);
}

// ---- prep: normalize rows (fp32) + write split-bf16 tiled layout -----------
// mode 0 (z): k-layout [hi | lo | hi];  mode 1 (e): [hi | hi | lo]
// groups g0,g1 are always hi.hi -> used by the probability path (K=128).
__global__ __launch_bounds__(256) void k_prep(const float* __restrict__ src,
                                              float* __restrict__ dstN,
                                              ushort* __restrict__ dstP, int mode) {
    int t = threadIdx.x, w = t >> 6, lane = t & 63;
    int row = blockIdx.x * 4 + w;
    float2 v = *reinterpret_cast<const float2*>(&src[(size_t)row * DIM + lane * 2]);
    float ss = v.x * v.x + v.y * v.y;
#pragma unroll
    for (int off = 32; off; off >>= 1) ss += __shfl_xor(ss, off);
    float nrm = fmaxf(sqrtf(ss), 1e-12f);
    float a = v.x / nrm, b = v.y / nrm;
    *reinterpret_cast<float2*>(&dstN[(size_t)row * DIM + lane * 2]) = make_float2(a, b);
    ushort ha = f2bf(a), hb = f2bf(b);
    ushort la = f2bf(a - bf2f(ha)), lb = f2bf(b - bf2f(hb));
    int T = row >> 7, r = row & 127, rx = r & 7, d = lane * 2;
    bf_store2(dstP, T, r, rx, d, ha, hb);
    if (mode == 0) {
        bf_store2(dstP, T, r, rx, 128 + d, la, lb);
        bf_store2(dstP, T, r, rx, 256 + d, ha, hb);
    } else {
        bf_store2(dstP, T, r, rx, 128 + d, ha, hb);
        bf_store2(dstP, T, r, rx, 256 + d, la, lb);
    }
}

// ---- phase 1: A(64 rows x K=384) resident in LDS; B streamed ---------------
// grid 1024: rg = b>>2 (256 groups of 64 rows), slice = b&3 (2048 codes).
// acc init = 2.0 (bias) so scores are positive; l accumulated on the hi.hi
// snapshot (after g1); argmax/m2 on the full split-K acc.
__global__ __launch_bounds__(256, 2) void k_p1(const ushort* __restrict__ Zp,
                                               const ushort* __restrict__ Ep,
                                               float4* __restrict__ part) {
    __shared__ ushort Au[24576];  // 48KB: 64 rows x 384 k, [g][512 chunks]
    __shared__ ushort Bu[8192];   // 16KB: 128 codes x 64 k
    int t = threadIdx.x, lane = t & 63, w = t >> 6;
    int rg = blockIdx.x >> 2, slice = blockIdx.x & 3;
    int wm = w >> 1, wn = w & 1;
    int n15 = lane & 15, quad = lane >> 4;
    int rx = n15 & 7;
    int T = rg >> 1, half = (rg & 1) << 9;

    // stage resident A once (12 chunks/thread)
#pragma unroll
    for (int it = 0; it < 12; ++it) {
        int chunk = it * 256 + t;
        gld_lds16(Zp + ((((size_t)(T * 6 + (chunk >> 9)) << 10) + half + (chunk & 511)) << 3),
                  &Au[chunk << 3]);
    }

    int aoff[2], boff[4];
#pragma unroll
    for (int ms = 0; ms < 2; ++ms) aoff[ms] = (wm * 32 + ms * 16 + n15) << 3;
#pragma unroll
    for (int ns = 0; ns < 4; ++ns) boff[ns] = (wn * 64 + ns * 16 + n15) << 3;

    float sm[8], s2v[8], sl[8];
    unsigned si[8];
#pragma unroll
    for (int s = 0; s < 8; ++s) { sm[s] = -1e30f; s2v[s] = -1e30f; sl[s] = 0.f; si[s] = 0u; }

    for (int ch = 0; ch < 16; ++ch) {
        int ctile = slice * 16 + ch;
        f32x4 acc[2][4];
#pragma unroll
        for (int i = 0; i < 2; ++i)
#pragma unroll
            for (int j = 0; j < 4; ++j) acc[i][j] = (f32x4)2.0f;

#pragma unroll
        for (int g = 0; g < 6; ++g) {
            __syncthreads();
            const ushort* gb = Ep + (((size_t)ctile * 6 + g) << 13);
#pragma unroll
            for (int rr = 0; rr < 4; ++rr) {
                int q = (rr * 256 + t) << 3;
                gld_lds16(gb + q, &Bu[q]);
            }
            __syncthreads();
            int gbase = g << 9;
#pragma unroll
            for (int kl = 0; kl < 2; ++kl) {
                int kx = (kl * 4 + quad) ^ rx;
                bf16x8 af[2], bfr[4];
#pragma unroll
                for (int ms = 0; ms < 2; ++ms)
                    af[ms] = *reinterpret_cast<const bf16x8*>(&Au[(gbase + aoff[ms] + kx) << 3]);
#pragma unroll
                for (int ns = 0; ns < 4; ++ns)
                    bfr[ns] = *reinterpret_cast<const bf16x8*>(&Bu[(boff[ns] + kx) << 3]);
#pragma unroll
                for (int ms = 0; ms < 2; ++ms)
#pragma unroll
                    for (int ns = 0; ns < 4; ++ns)
                        acc[ms][ns] = MFMA16(af[ms], bfr[ns], acc[ms][ns]);
            }
            if (g == 1) {
                // snapshot: acc = 2 + s_hh  -> softmax-denominator on hi.hi basis
#pragma unroll
                for (int ms = 0; ms < 2; ++ms)
#pragma unroll
                    for (int reg = 0; reg < 4; ++reg) {
                        int s = ms * 4 + reg;
                        float e0 = __expf(fmaf(acc[ms][0][reg], 10.f, -20.f));
                        float e1 = __expf(fmaf(acc[ms][1][reg], 10.f, -20.f));
                        float e2 = __expf(fmaf(acc[ms][2][reg], 10.f, -20.f));
                        float e3 = __expf(fmaf(acc[ms][3][reg], 10.f, -20.f));
                        sl[s] += (e0 + e1) + (e2 + e3);
                    }
            }
        }
        // argmax / m2 on full split-K scores (biased)
        unsigned cbase = slice * 2048 + ch * 128 + wn * 64 + n15;
#pragma unroll
        for (int ms = 0; ms < 2; ++ms)
#pragma unroll
            for (int reg = 0; reg < 4; ++reg) {
                int s = ms * 4 + reg;
                float m = sm[s], m2 = s2v[s];
                unsigned idx = si[s];
#pragma unroll
                for (int ns = 0; ns < 4; ++ns) {
                    float v = acc[ms][ns][reg];
                    unsigned code = cbase + ns * 16;
                    float lo = fminf(v, m);
                    m2 = fmaxf(m2, lo);
                    idx = (v > m) ? code : idx;
                    m = fmaxf(v, m);
                }
                sm[s] = m; s2v[s] = m2; si[s] = idx;
            }
    }
    // cross-lane merge over the 16-lane col group
#pragma unroll
    for (int ms = 0; ms < 2; ++ms)
#pragma unroll
        for (int reg = 0; reg < 4; ++reg) {
            int s = ms * 4 + reg;
            float m = sm[s], m2 = s2v[s], l = sl[s];
            unsigned idx = si[s];
#pragma unroll
            for (int off = 1; off < 16; off <<= 1) {
                float om  = __shfl_xor(m, off);
                float om2 = __shfl_xor(m2, off);
                float ol  = __shfl_xor(l, off);
                unsigned oi = (unsigned)__shfl_xor((int)idx, off);
                m2 = fmaxf(fmaxf(m2, om2), fminf(m, om));
                l += ol;
                bool take = (om > m) || (om == m && oi < idx);
                idx = take ? oi : idx;
                m = fmaxf(m, om);
            }
            if (n15 == 0) {
                int row = rg * 64 + wm * 32 + ms * 16 + quad * 4 + reg;
                part[slice * N_ROWS + row] = make_float4(m, l, __uint_as_float(idx), m2);
            }
        }
}

// ---- merge 4 slice-partials per row; flag rows with tiny top-2 gap ---------
__global__ __launch_bounds__(256) void k_merge(const float4* __restrict__ part,
                                               float* __restrict__ linv_out,
                                               int* __restrict__ idx_out,
                                               int* __restrict__ flaglist,
                                               int* __restrict__ nflag) {
    int row = blockIdx.x * 256 + threadIdx.x;
    float m = -1e30f, m2 = -1e30f, l = 0.f;
    unsigned idx = 0u;
#pragma unroll
    for (int s = 0; s < 4; ++s) {
        float4 p = part[s * N_ROWS + row];
        float om = p.x, ol = p.y, om2 = p.w;
        unsigned oi = __float_as_uint(p.z);
        m2 = fmaxf(fmaxf(m2, om2), fminf(m, om));
        l += ol;
        bool take = (om > m) || (om == m && oi < idx);
        idx = take ? oi : idx;
        m = fmaxf(m, om);
    }
    linv_out[row] = 1.0f / l;
    idx_out[row] = (int)idx;
    if (m - m2 < EPSF) {
        int pos = atomicAdd(nflag, 1);
        flaglist[pos] = row;
    }
}

// ---- fp64 exact re-argmax for flagged rows ---------------------------------
__global__ __launch_bounds__(256) void k_refine(const float* __restrict__ zN,
                                                const float* __restrict__ eN,
                                                const int* __restrict__ flaglist,
                                                const int* __restrict__ nflag,
                                                unsigned long long* __restrict__ refbuf) {
    int nf = *nflag;
    if (nf > N_ROWS) nf = N_ROWS;
    int csl = blockIdx.x & 7;
    int t = threadIdx.x;
    __shared__ float zl[DIM];
    for (int fi = blockIdx.x >> 3; fi < nf; fi += 512) {
        int row = flaglist[fi];
        __syncthreads();
        if (t < DIM) zl[t] = zN[(size_t)row * DIM + t];
        __syncthreads();
        double best = -1e300;
        int bc = 0x7FFFFFFF;
#pragma unroll
        for (int j = 0; j < 4; ++j) {
            int c = csl * 1024 + j * 256 + t;
            const float* e = &eN[(size_t)c * DIM];
            double s = 0.0;
#pragma unroll 8
            for (int d = 0; d < DIM; ++d) s += (double)zl[d] * (double)e[d];
            if (s > best) { best = s; bc = c; }
        }
#pragma unroll
        for (int off = 1; off < 64; off <<= 1) {
            double ob = __shfl_xor(best, off);
            int oc = __shfl_xor(bc, off);
            if (ob > best || (ob == best && oc < bc)) { best = ob; bc = oc; }
        }
        if ((t & 63) == 0) {
            unsigned long long u = (unsigned long long)__double_as_longlong(best);
            u = (u & 0x8000000000000000ull) ? ~u : (u | 0x8000000000000000ull);
            unsigned long long key = (u & ~0x1FFFull) | (unsigned long long)(8191 - bc);
            atomicMax(&refbuf[row], key);
        }
    }
}

__global__ __launch_bounds__(256) void k_fixidx(const int* __restrict__ flaglist,
                                                const int* __restrict__ nflag,
                                                const unsigned long long* __restrict__ refbuf,
                                                int* __restrict__ idx) {
    int i = blockIdx.x * 256 + threadIdx.x;
    int nf = *nflag;
    if (nf > N_ROWS) nf = N_ROWS;
    if (i < nf) {
        int row = flaglist[i];
        idx[row] = 8191 - (int)(refbuf[row] & 0x1FFFull);
    }
}

__global__ void k_counts(const int* __restrict__ idx, unsigned int* __restrict__ counts) {
    int i = blockIdx.x * 256 + threadIdx.x;
    atomicAdd(&counts[idx[i]], 1u);
}

// ---- phase 2: K=128 (hi.hi) GEMM, codes resident in LDS --------------------
// grid 1024: cg = b>>4 (64 code tiles), rs = b&15 (8 row-tiles each).
// P_sum[k] += exp(10*s_hh) * linv;  acc bias 2.0 matches p1's snapshot basis.
__global__ __launch_bounds__(256, 3) void k_p2(const ushort* __restrict__ Zp,
                                               const ushort* __restrict__ Ep,
                                               const float* __restrict__ linv_in,
                                               float* __restrict__ P_sum) {
    __shared__ ushort Ac[16384];  // 32KB: 128 codes x 128 k (g0,g1)
    __shared__ ushort Bu[8192];   // 16KB: 128 rows x 64 k
    int t = threadIdx.x, lane = t & 63, w = t >> 6;
    int cg = blockIdx.x >> 4, rs = blockIdx.x & 15;
    int wm = w >> 1, wn = w & 1;
    int n15 = lane & 15, quad = lane >> 4;
    int rx = n15 & 7;

    // stage resident codes (8 chunks/thread); groups 0,1 are contiguous
#pragma unroll
    for (int it = 0; it < 8; ++it) {
        int chunk = it * 256 + t;
        gld_lds16(Ep + ((((size_t)cg * 6 << 10) + chunk) << 3), &Ac[chunk << 3]);
    }

    int aoff[4], boff[4];
#pragma unroll
    for (int ms = 0; ms < 4; ++ms) aoff[ms] = (wm * 64 + ms * 16 + n15) << 3;
#pragma unroll
    for (int ns = 0; ns < 4; ++ns) boff[ns] = (wn * 64 + ns * 16 + n15) << 3;

    float pacc[16];
#pragma unroll
    for (int s = 0; s < 16; ++s) pacc[s] = 0.f;

    for (int ch = 0; ch < 8; ++ch) {
        int rtile = rs * 8 + ch;
        f32x4 acc[4][4];
#pragma unroll
        for (int i = 0; i < 4; ++i)
#pragma unroll
            for (int j = 0; j < 4; ++j) acc[i][j] = (f32x4)2.0f;

#pragma unroll
        for (int g = 0; g < 2; ++g) {
            __syncthreads();
            const ushort* gb = Zp + (((size_t)rtile * 6 + g) << 13);
#pragma unroll
            for (int rr = 0; rr < 4; ++rr) {
                int q = (rr * 256 + t) << 3;
                gld_lds16(gb + q, &Bu[q]);
            }
            __syncthreads();
            int gbase = g << 10;
#pragma unroll
            for (int kl = 0; kl < 2; ++kl) {
                int kx = (kl * 4 + quad) ^ rx;
                bf16x8 af[4], bfr[4];
#pragma unroll
                for (int ms = 0; ms < 4; ++ms)
                    af[ms] = *reinterpret_cast<const bf16x8*>(&Ac[(gbase + aoff[ms] + kx) << 3]);
#pragma unroll
                for (int ns = 0; ns < 4; ++ns)
                    bfr[ns] = *reinterpret_cast<const bf16x8*>(&Bu[(boff[ns] + kx) << 3]);
#pragma unroll
                for (int ms = 0; ms < 4; ++ms)
#pragma unroll
                    for (int ns = 0; ns < 4; ++ns)
                        acc[ms][ns] = MFMA16(af[ms], bfr[ns], acc[ms][ns]);
            }
        }
        int rbase = rtile * 128 + wn * 64 + n15;
        float li[4];
#pragma unroll
        for (int ns = 0; ns < 4; ++ns) li[ns] = linv_in[rbase + ns * 16];
#pragma unroll
        for (int ms = 0; ms < 4; ++ms)
#pragma unroll
            for (int reg = 0; reg < 4; ++reg) {
                int s = ms * 4 + reg;
                float p = pacc[s];
#pragma unroll
                for (int ns = 0; ns < 4; ++ns)
                    p = fmaf(__expf(fmaf(acc[ms][ns][reg], 10.f, -20.f)), li[ns], p);
                pacc[s] = p;
            }
    }
#pragma unroll
    for (int s = 0; s < 16; ++s) {
#pragma unroll
        for (int off = 1; off < 16; off <<= 1) pacc[s] += __shfl_xor(pacc[s], off);
    }
    if (n15 == 0) {
#pragma unroll
        for (int ms = 0; ms < 4; ++ms)
#pragma unroll
            for (int reg = 0; reg < 4; ++reg)
                atomicAdd(&P_sum[cg * 128 + wm * 64 + ms * 16 + quad * 4 + reg],
                          pacc[ms * 4 + reg]);
    }
}

// ---- gather z_q_st + commit-loss partial -----------------------------------
__global__ __launch_bounds__(256) void k_gather(const float* __restrict__ z,
                                                const float* __restrict__ W,
                                                const int* __restrict__ idx,
                                                float* __restrict__ out,
                                                float* __restrict__ mse) {
    int v = blockIdx.x * 256 + threadIdx.x;
    int row = v >> 5;
    int id = idx[row];
    float4 q = *reinterpret_cast<const float4*>(&W[(size_t)id * DIM + (v & 31) * 4]);
    float4 zz = *reinterpret_cast<const float4*>(&z[(size_t)v * 4]);
    float dx = q.x - zz.x, dy = q.y - zz.y, dz = q.z - zz.z, dw = q.w - zz.w;
    *reinterpret_cast<float4*>(&out[(size_t)v * 4]) = q;
    float e = dx * dx + dy * dy + dz * dz + dw * dw;
#pragma unroll
    for (int off = 1; off < 64; off <<= 1) e += __shfl_xor(e, off);
    __shared__ float red[4];
    int lane = threadIdx.x & 63, wv = threadIdx.x >> 6;
    if (lane == 0) red[wv] = e;
    __syncthreads();
    if (threadIdx.x == 0) atomicAdd(mse, red[0] + red[1] + red[2] + red[3]);
}

// ---- finalize scalars -------------------------------------------------------
__global__ __launch_bounds__(256) void k_finalize(const unsigned int* __restrict__ counts,
                                                  const float* __restrict__ P_sum,
                                                  const float* __restrict__ mse,
                                                  float* __restrict__ out) {
    int t = threadIdx.x;
    float s1 = 0.f, s2 = 0.f;
    for (int k = t; k < K_CODES; k += 256) {
        float em = (float)counts[k] * (1.0f / 16384.0f);
        s1 += em * logf(em + 1e-8f);
        float p = P_sum[k] * (1.0f / 16384.0f) + 1e-8f;
        s2 += p * logf(p);
    }
#pragma unroll
    for (int off = 1; off < 64; off <<= 1) {
        s1 += __shfl_xor(s1, off);
        s2 += __shfl_xor(s2, off);
    }
    __shared__ float r1[4], r2[4];
    int lane = t & 63, wv = t >> 6;
    if (lane == 0) { r1[wv] = s1; r2[wv] = s2; }
    __syncthreads();
    if (t == 0) {
        float S1 = r1[0] + r1[1] + r1[2] + r1[3];
        float S2 = r2[0] + r2[1] + r2[2] + r2[3];
        out[2097152] = 1.25f * mse[0] * (1.0f / 2097152.0f);
        out[2097153] = expf(-S1);
        out[2097154] = -S2;
    }
}

extern "C" void kernel_launch(void* const* d_in, const int* in_sizes, int n_in,
                              void* d_out, int out_size, void* d_ws, size_t ws_size,
                              hipStream_t stream) {
    (void)in_sizes; (void)n_in; (void)out_size; (void)ws_size;
    const float* z = (const float*)d_in[0];
    const float* W = (const float*)d_in[1];
    float* ws = (float*)d_ws;
    float* eN = ws + OFF_EN;
    float* zN = ws + OFF_ZN;
    ushort* Ep = (ushort*)(ws + OFF_EP);
    ushort* Zp = (ushort*)(ws + OFF_ZP);
    float4* part = (float4*)(ws + OFF_PART);
    float* linv = ws + OFF_LINV;
    int* idx = (int*)(ws + OFF_IDX);
    int* flaglist = (int*)(ws + OFF_FLAGLIST);
    unsigned int* counts = (unsigned int*)(ws + OFF_CNT);
    float* P = ws + OFF_P;
    float* mse = ws + OFF_MSE;
    int* nflag = (int*)(ws + OFF_NFLAG);
    unsigned long long* refbuf = (unsigned long long*)(ws + OFF_REFBUF);
    float* out = (float*)d_out;

    hipMemsetAsync(ws + OFF_CNT, 0, MEMSET_BYTES, stream);
    k_prep<<<N_ROWS / 4, 256, 0, stream>>>(z, zN, Zp, 0);
    k_prep<<<K_CODES / 4, 256, 0, stream>>>(W, eN, Ep, 1);
    k_p1<<<1024, 256, 0, stream>>>(Zp, Ep, part);
    k_merge<<<N_ROWS / 256, 256, 0, stream>>>(part, linv, idx, flaglist, nflag);
    k_refine<<<4096, 256, 0, stream>>>(zN, eN, flaglist, nflag, refbuf);
    k_fixidx<<<64, 256, 0, stream>>>(flaglist, nflag, refbuf, idx);
    k_counts<<<N_ROWS / 256, 256, 0, stream>>>(idx, counts);
    k_p2<<<1024, 256, 0, stream>>>(Zp, Ep, linv, P);
    k_gather<<<(N_ROWS * DIM / 4) / 256, 256, 0, stream>>>(z, W, idx, out, mse);
    k_finalize<<<1, 256, 0, stream>>>(counts, P, mse, out);
}